// Round 8
// baseline (803.953 us; speedup 1.0000x reference)
//
#include <hip/hip_runtime.h>
#include <hip/hip_bf16.h>

#define NPTS 262144
#define DIM  128
#define KC   20
#define MP   10
#define LNEPS 1e-5f
#define EPSI  0.05f
#define CCAP  65536

typedef _Float16 half8 __attribute__((ext_vector_type(8)));
typedef float f32x4 __attribute__((ext_vector_type(4)));

union H8U4 { half8 h; uint4 u; };

// workspace layout (float offsets)
#define WS_PN     0          // 25600 normalized protos f32
#define WS_PHI    25600      // 13312 floats (208x128 f16 hi)
#define WS_PLO    38912      // 13312 floats (f16 lo)
#define WS_F      52224      // 25600 f accumulator
#define WS_NCOUNT 77824      // 200
#define WS_CCNT   78024      // 8 ints: ccnt, tix[0..3]
#define WS_UH     78032      // 600 u history (3 x 200)
#define WS_SK     78632      // 20
#define WS_BC     78652      // 20
#define WS_PSB    78672      // 40*256 partials
#define WS_PR     88912      // 200*1024 row-sum partials
#define WS_EXPV   293712     // N*12 (10 + 2 pad)
#define WS_CIDX   3439440    // 65536 ints
// total 3504976 floats = 14.0 MB

__device__ __forceinline__ half8 lds_h8(const uint4* p) {
    return *reinterpret_cast<const half8*>(p);
}

// ---- normalize prototypes, emit f32 + f16 hi/lo (rows 200..207 zero-padded)
__global__ __launch_bounds__(64) void k_norm_protos(
    const float* __restrict__ pr, float* __restrict__ pn,
    _Float16* __restrict__ phi, _Float16* __restrict__ plo)
{
    int j = blockIdx.x, l = threadIdx.x;
    if (j < 200) {
        float x0 = pr[(size_t)j*128 + l], x1 = pr[(size_t)j*128 + 64 + l];
        float ss = x0*x0 + x1*x1;
        #pragma unroll
        for (int off = 32; off > 0; off >>= 1) ss += __shfl_xor(ss, off);
        float dn = fmaxf(sqrtf(ss), 1e-12f);
        float y0 = x0/dn, y1 = x1/dn;
        pn[(size_t)j*128 + l]      = y0;
        pn[(size_t)j*128 + 64 + l] = y1;
        _Float16 h0 = (_Float16)y0, h1 = (_Float16)y1;
        phi[(size_t)j*128 + l]      = h0;
        phi[(size_t)j*128 + 64 + l] = h1;
        plo[(size_t)j*128 + l]      = (_Float16)(y0 - (float)h0);
        plo[(size_t)j*128 + 64 + l] = (_Float16)(y1 - (float)h1);
    } else {
        phi[(size_t)j*128 + l] = (_Float16)0.f;  phi[(size_t)j*128 + 64 + l] = (_Float16)0.f;
        plo[(size_t)j*128 + l] = (_Float16)0.f;  plo[(size_t)j*128 + 64 + l] = (_Float16)0.f;
    }
}

// process 8 cols [BASE, BASE+8) for one point: update static-indexed class maxes,
// write expv for own class. Compile-time class split (<=2 classes per 8 cols).
#define PROC8(BASEX, va, vb) do { \
    constexpr int B_  = (BASEX); \
    constexpr int KA_ = (B_/10 > 19) ? 19 : B_/10; \
    constexpr int E_  = (B_ >= 200) ? 0 : ((B_+8 > 200) ? (200-B_) : 8); \
    constexpr int SR_ = (KA_+1)*10 - B_; \
    constexpr int SPL_ = (SR_ < E_) ? SR_ : E_; \
    constexpr int KB_ = (SPL_ < E_) ? (KA_+1) : KA_; \
    float vv[8] = {va.x, va.y, va.z, va.w, vb.x, vb.y, vb.z, vb.w}; \
    _Pragma("unroll") \
    for (int j = 0; j < SPL_; ++j) mlA[KA_] = fmaxf(mlA[KA_], vv[j]); \
    _Pragma("unroll") \
    for (int j = SPL_; j < E_; ++j) mlA[KB_] = fmaxf(mlA[KB_], vv[j]); \
    if (E_ > 0 && g == KA_) { \
        _Pragma("unroll") \
        for (int j = 0; j < SPL_; ++j) { \
            float e = expf(vv[j] / EPSI); \
            expv[n12 + (B_ + j - 10*KA_)] = e; se += e; } \
    } \
    if (KB_ != KA_ && g == KB_) { \
        _Pragma("unroll") \
        for (int j = SPL_; j < E_; ++j) { \
            float e = expf(vv[j] / EPSI); \
            expv[n12 + (B_ + j - 10*KB_)] = e; se += e; } \
    } \
} while (0)

// per-nt: plog stores from acc, wave-private LDS transpose, streamed class maxes
#define DO_NT(NT) do { \
    /* plog float4 stores */ \
    _Pragma("unroll") \
    for (int mt = 0; mt < 2; ++mt) \
        if ((NT) < 12 || l4 < 2) { \
            float4 sv; sv.x = acc[mt][NT][0]; sv.y = acc[mt][NT][1]; \
            sv.z = acc[mt][NT][2]; sv.w = acc[mt][NT][3]; \
            *reinterpret_cast<float4*>( \
                &plog[(size_t)(pbase + w*32 + mt*16 + l15)*200 + (NT)*16 + l4*4]) = sv; \
        } \
    /* wave-private transpose via LDS (same-wave in-order, no barrier) */ \
    { float4 wv; \
      wv.x = acc[0][NT][0]; wv.y = acc[0][NT][1]; wv.z = acc[0][NT][2]; wv.w = acc[0][NT][3]; \
      *reinterpret_cast<float4*>(&ew[l15*20 + l4*4]) = wv; \
      wv.x = acc[1][NT][0]; wv.y = acc[1][NT][1]; wv.z = acc[1][NT][2]; wv.w = acc[1][NT][3]; \
      *reinterpret_cast<float4*>(&ew[(16 + l15)*20 + l4*4]) = wv; } \
    { const float* rp = ew + (lane & 31)*20 + (lane >> 5)*8; \
      float4 va = *reinterpret_cast<const float4*>(rp); \
      float4 vb = *reinterpret_cast<const float4*>(rp + 4); \
      if (lane < 32) { PROC8((NT)*16,     va, vb); } \
      else           { PROC8((NT)*16 + 8, va, vb); } } \
} while (0)

// ---- fused main kernel: grid 256 x 512thr. B staged once in LDS; 4 chunks of
//  256 pts; barrier-free main loop; per-wave epilogue (out_seg/expv/correct);
//  deterministic class partials + last-block sB reduce via fence+ticket.
__global__ __launch_bounds__(512, 1) void k_fused(
    const float* __restrict__ feat, const int* __restrict__ gt,
    const _Float16* __restrict__ phi, const _Float16* __restrict__ plo,
    const float* __restrict__ fg, const float* __restrict__ fb,
    const float* __restrict__ mg, const float* __restrict__ mb,
    float* __restrict__ out_seg, float* __restrict__ plog,
    float* __restrict__ expv, float* __restrict__ psb,
    int* __restrict__ cidx, int* __restrict__ ccnt, int* __restrict__ tix,
    float* __restrict__ sk, float* __restrict__ Bc)
{
    __shared__ __align__(16) char ldsb[106496];
    __shared__ __align__(16) float ewaveAll[8][640];   // 32 rows x pitch 20
    __shared__ float sumS[1024];
    __shared__ int   gtS[1024];
    __shared__ float part[320];
    __shared__ int   tickS;

    uint4* bHi = (uint4*)ldsb;
    uint4* bLo = (uint4*)(ldsb + 53248);

    const int t = threadIdx.x, blk = blockIdx.x;
    const int w = t >> 6, lane = t & 63;
    const int l15 = lane & 15, l4 = lane >> 4;
    float* ew = ewaveAll[w];

    // ---- stage full B (swizzled slot = s ^ (row&15)), once per block
    {
        const uint4* phi4 = (const uint4*)phi;
        const uint4* plo4 = (const uint4*)plo;
        #pragma unroll
        for (int ii = 0; ii < 13; ++ii) {
            int idx = ii*512 + t;
            bool ishi = idx < 3328;
            int ridx = ishi ? idx : idx - 3328;
            int dst = (ridx & ~15) | ((ridx & 15) ^ ((ridx >> 4) & 15));
            uint4 vv = ishi ? phi4[ridx] : plo4[ridx];
            (ishi ? bHi : bLo)[dst] = vv;
        }
    }
    __syncthreads();

    const float4* gfeat = (const float4*)feat;

    #pragma unroll 1
    for (int ch = 0; ch < 4; ++ch) {
        const int pbase = (ch*256 + blk) * 256;

        // ---- A direct loads in fragment layout
        float4 A[2][4][2];
        #pragma unroll
        for (int mt = 0; mt < 2; ++mt) {
            size_t rb = (size_t)(pbase + w*32 + mt*16 + l15) * 32;
            #pragma unroll
            for (int kst = 0; kst < 4; ++kst)
                #pragma unroll
                for (int h = 0; h < 2; ++h)
                    A[mt][kst][h] = gfeat[rb + kst*8 + l4*2 + h];
        }
        float4 G[4][2], Bb[4][2];
        {
            const float4* fg4 = (const float4*)fg;
            const float4* fb4 = (const float4*)fb;
            #pragma unroll
            for (int kst = 0; kst < 4; ++kst)
                #pragma unroll
                for (int h = 0; h < 2; ++h) {
                    G[kst][h]  = fg4[kst*8 + l4*2 + h];
                    Bb[kst][h] = fb4[kst*8 + l4*2 + h];
                }
        }

        // ---- LN + l2n per mt (4-lane group reduce), f16 hi/lo fragments
        half8 fah[2][4], fal[2][4];
        #pragma unroll
        for (int mt = 0; mt < 2; ++mt) {
            float s0 = 0.f;
            #pragma unroll
            for (int kst = 0; kst < 4; ++kst)
                #pragma unroll
                for (int h = 0; h < 2; ++h) {
                    float4 v = A[mt][kst][h];
                    s0 += v.x + v.y + v.z + v.w;
                }
            s0 += __shfl_xor(s0, 16); s0 += __shfl_xor(s0, 32);
            float mean = s0 * (1.f/128.f);
            float s1 = 0.f;
            #pragma unroll
            for (int kst = 0; kst < 4; ++kst)
                #pragma unroll
                for (int h = 0; h < 2; ++h) {
                    float4 v = A[mt][kst][h];
                    float a = v.x-mean, b = v.y-mean, c = v.z-mean, d = v.w-mean;
                    s1 += a*a + b*b + c*c + d*d;
                }
            s1 += __shfl_xor(s1, 16); s1 += __shfl_xor(s1, 32);
            float rstd = rsqrtf(s1 * (1.f/128.f) + LNEPS);
            float s2 = 0.f;
            #pragma unroll
            for (int kst = 0; kst < 4; ++kst)
                #pragma unroll
                for (int h = 0; h < 2; ++h) {
                    float4 v = A[mt][kst][h];
                    float4 g = G[kst][h], bb = Bb[kst][h];
                    v.x = (v.x-mean)*rstd*g.x + bb.x;
                    v.y = (v.y-mean)*rstd*g.y + bb.y;
                    v.z = (v.z-mean)*rstd*g.z + bb.z;
                    v.w = (v.w-mean)*rstd*g.w + bb.w;
                    A[mt][kst][h] = v;
                    s2 += v.x*v.x + v.y*v.y + v.z*v.z + v.w*v.w;
                }
            s2 += __shfl_xor(s2, 16); s2 += __shfl_xor(s2, 32);
            float rl2 = 1.f / fmaxf(sqrtf(s2), 1e-12f);
            #pragma unroll
            for (int kst = 0; kst < 4; ++kst) {
                float4 va = A[mt][kst][0], vb = A[mt][kst][1];
                va.x*=rl2; va.y*=rl2; va.z*=rl2; va.w*=rl2;
                vb.x*=rl2; vb.y*=rl2; vb.z*=rl2; vb.w*=rl2;
                H8U4 h, lo;
                h.h[0]=(_Float16)va.x; h.h[1]=(_Float16)va.y; h.h[2]=(_Float16)va.z; h.h[3]=(_Float16)va.w;
                h.h[4]=(_Float16)vb.x; h.h[5]=(_Float16)vb.y; h.h[6]=(_Float16)vb.z; h.h[7]=(_Float16)vb.w;
                lo.h[0]=(_Float16)(va.x-(float)h.h[0]); lo.h[1]=(_Float16)(va.y-(float)h.h[1]);
                lo.h[2]=(_Float16)(va.z-(float)h.h[2]); lo.h[3]=(_Float16)(va.w-(float)h.h[3]);
                lo.h[4]=(_Float16)(vb.x-(float)h.h[4]); lo.h[5]=(_Float16)(vb.y-(float)h.h[5]);
                lo.h[6]=(_Float16)(vb.z-(float)h.h[6]); lo.h[7]=(_Float16)(vb.w-(float)h.h[7]);
                fah[mt][kst] = h.h;
                fal[mt][kst] = lo.h;
            }
        }

        // ---- barrier-free MFMA GEMM, swapped operands (lane l15 = point)
        f32x4 acc[2][13];
        #pragma unroll
        for (int mt = 0; mt < 2; ++mt)
            #pragma unroll
            for (int nt = 0; nt < 13; ++nt)
                acc[mt][nt] = (f32x4){0.f,0.f,0.f,0.f};

        #pragma unroll
        for (int nt = 0; nt < 13; ++nt) {
            const uint4* bH = bHi + (nt*16 + l15)*16;
            const uint4* bL = bLo + (nt*16 + l15)*16;
            #pragma unroll
            for (int kst = 0; kst < 4; ++kst) {
                int sl = (kst*4 + l4) ^ l15;
                half8 bh = lds_h8(bH + sl);
                half8 bl = lds_h8(bL + sl);
                acc[0][nt] = __builtin_amdgcn_mfma_f32_16x16x32_f16(bh, fah[0][kst], acc[0][nt], 0,0,0);
                acc[0][nt] = __builtin_amdgcn_mfma_f32_16x16x32_f16(bh, fal[0][kst], acc[0][nt], 0,0,0);
                acc[0][nt] = __builtin_amdgcn_mfma_f32_16x16x32_f16(bl, fah[0][kst], acc[0][nt], 0,0,0);
                acc[0][nt] = __builtin_amdgcn_mfma_f32_16x16x32_f16(bl, fal[0][kst], acc[0][nt], 0,0,0);
                acc[1][nt] = __builtin_amdgcn_mfma_f32_16x16x32_f16(bh, fah[1][kst], acc[1][nt], 0,0,0);
                acc[1][nt] = __builtin_amdgcn_mfma_f32_16x16x32_f16(bh, fal[1][kst], acc[1][nt], 0,0,0);
                acc[1][nt] = __builtin_amdgcn_mfma_f32_16x16x32_f16(bl, fah[1][kst], acc[1][nt], 0,0,0);
                acc[1][nt] = __builtin_amdgcn_mfma_f32_16x16x32_f16(bl, fal[1][kst], acc[1][nt], 0,0,0);
            }
        }

        // ---- per-wave epilogue (no block barrier)
        const int p_ = lane & 31;
        const int n = pbase + w*32 + p_;
        const int g = gt[n];
        const size_t n12 = (size_t)n * 12;
        float mlA[20];
        float se = 0.f;
        #pragma unroll
        for (int k = 0; k < 20; ++k) mlA[k] = -__builtin_inff();

        DO_NT(0); DO_NT(1); DO_NT(2); DO_NT(3); DO_NT(4); DO_NT(5); DO_NT(6);
        DO_NT(7); DO_NT(8); DO_NT(9); DO_NT(10); DO_NT(11); DO_NT(12);

        // combine lane pair (h0 holds cols 0-7 mod 16, h1 holds 8-15 mod 16)
        #pragma unroll
        for (int k = 0; k < 20; ++k) {
            float o = __shfl_xor(mlA[k], 32);
            mlA[k] = fmaxf(mlA[k], o);
        }
        se += __shfl_xor(se, 32);

        if (lane < 32) {
            float s0 = 0.f;
            #pragma unroll
            for (int k = 0; k < 20; ++k) s0 += mlA[k];
            float mean = s0 / 20.f;
            float s1 = 0.f;
            #pragma unroll
            for (int k = 0; k < 20; ++k) { float d = mlA[k]-mean; s1 += d*d; }
            float rstd = rsqrtf(s1 / 20.f + LNEPS);
            float bv = -1e30f; int bk = 0;
            #pragma unroll
            for (int q = 0; q < 5; ++q) {
                float4 yv;
                float y0 = (mlA[q*4+0]-mean)*rstd*mg[q*4+0] + mb[q*4+0];
                float y1 = (mlA[q*4+1]-mean)*rstd*mg[q*4+1] + mb[q*4+1];
                float y2 = (mlA[q*4+2]-mean)*rstd*mg[q*4+2] + mb[q*4+2];
                float y3 = (mlA[q*4+3]-mean)*rstd*mg[q*4+3] + mb[q*4+3];
                if (y0 > bv) { bv = y0; bk = q*4+0; }
                if (y1 > bv) { bv = y1; bk = q*4+1; }
                if (y2 > bv) { bv = y2; bk = q*4+2; }
                if (y3 > bv) { bv = y3; bk = q*4+3; }
                yv.x = y0; yv.y = y1; yv.z = y2; yv.w = y3;
                *reinterpret_cast<float4*>(&out_seg[(size_t)n*20 + q*4]) = yv;
            }
            if (bk == g) {
                int slot = atomicAdd(ccnt, 1);
                if (slot < CCAP) cidx[slot] = n;
            }
            sumS[ch*256 + w*32 + p_] = se;
            gtS[ch*256 + w*32 + p_]  = g;
        }
    }

    // ---- deterministic per-block class partials over all 1024 points
    __syncthreads();
    if (t < 160) {
        int c = t >> 3, o = t & 7;
        float cnt = 0.f, sm = 0.f;
        for (int i = o*128; i < o*128 + 128; ++i)
            if (gtS[i] == c) { cnt += 1.f; sm += sumS[i]; }
        part[t] = cnt; part[160 + t] = sm;
    }
    __syncthreads();
    if (t < 20) {
        float cnt = 0.f, sm = 0.f;
        #pragma unroll
        for (int o = 0; o < 8; ++o) { cnt += part[t*8+o]; sm += part[160 + t*8+o]; }
        psb[(size_t)t*256 + blk]      = cnt;
        psb[(size_t)(20+t)*256 + blk] = sm;
    }

    // ---- fence + ticket: last block reduces psb -> Bc, sk (deterministic)
    __threadfence();
    __syncthreads();
    if (t == 0) tickS = atomicAdd(tix, 1);
    __syncthreads();
    if (tickS == 255) {
        __threadfence();
        int rw = t >> 6, rl = t & 63;
        for (int r = rw; r < 40; r += 8) {
            float s = psb[(size_t)r*256 + rl]       + psb[(size_t)r*256 + 64 + rl]
                    + psb[(size_t)r*256 + 128 + rl] + psb[(size_t)r*256 + 192 + rl];
            #pragma unroll
            for (int off = 32; off > 0; off >>= 1) s += __shfl_xor(s, off);
            if (rl == 0) { if (r < 20) Bc[r] = s; else sk[r-20] = s; }
        }
    }
}

// ---- sinkhorn row pass with fused v-chain + last-block u reduce
__global__ __launch_bounds__(256) void k_row(int iter,
    const int* __restrict__ gt, const float* __restrict__ expv,
    float* __restrict__ uh, const float* __restrict__ sk,
    const float* __restrict__ Bc, float* __restrict__ pr,
    int* __restrict__ tix)
{
    __shared__ float prodS[2560];
    __shared__ int gtS[256];
    __shared__ int tickS;
    int t = threadIdx.x, b = blockIdx.x;
    int n = b*256 + t;
    int g = gt[n];
    float e[10];
    {
        const float4* e4 = (const float4*)(expv + (size_t)n*12);
        float4 ea = e4[0], eb = e4[1], ec = e4[2];
        e[0]=ea.x; e[1]=ea.y; e[2]=ea.z; e[3]=ea.w;
        e[4]=eb.x; e[5]=eb.y; e[6]=eb.z; e[7]=eb.w;
        e[8]=ec.x; e[9]=ec.y;
    }
    float skg = sk[g];
    float v = (skg > 0.f) ? 1.f/skg : 1.f;
    float B = Bc[g];
    float Bs = (B > 0.f) ? B : 1.f;
    for (int c = 1; c < iter; ++c) {
        const float* uc = uh + (c-1)*200 + g*10;
        float sc = 0.f;
        #pragma unroll
        for (int m = 0; m < 10; ++m) sc += e[m]*uc[m];
        v = (sc > 0.f) ? 1.f/(Bs*sc) : v/Bs;
    }
    #pragma unroll
    for (int m = 0; m < 10; ++m) prodS[t*10+m] = e[m]*v;
    gtS[t] = g;
    __syncthreads();
    if (t < 200) {
        int kk = t / 10, mm = t % 10;
        float acc = 0.f;
        for (int i = 0; i < 256; ++i)
            if (gtS[i] == kk) acc += prodS[i*10+mm];
        pr[(size_t)t*1024 + b] = acc;
    }
    __threadfence();
    __syncthreads();
    if (t == 0) tickS = atomicAdd(tix, 1);
    __syncthreads();
    if (tickS == 1023) {
        __threadfence();
        int rw = t >> 6, rl = t & 63;
        for (int j = rw; j < 200; j += 4) {
            float s = 0.f;
            #pragma unroll
            for (int i = 0; i < 16; ++i) s += pr[(size_t)j*1024 + i*64 + rl];
            #pragma unroll
            for (int off = 32; off > 0; off >>= 1) s += __shfl_xor(s, off);
            if (rl == 0) {
                float uprev = (iter == 1) ? 1.f : uh[(iter-2)*200 + j];
                uh[(iter-1)*200 + j] = (s > 0.f) ? 1.f/(10.f*s) : uprev*0.1f;
            }
        }
    }
}

// ---- assignment + f/ncount accumulation
__global__ __launch_bounds__(256) void k_post(
    const int* __restrict__ gt, const float* __restrict__ expv,
    const float* __restrict__ u,
    const int* __restrict__ cidx, const int* __restrict__ ccnt,
    const float* __restrict__ feat, const float* __restrict__ fg,
    const float* __restrict__ fb,
    float* __restrict__ ptarget, float* __restrict__ facc,
    float* __restrict__ ncount)
{
    int t = threadIdx.x;
    {
        int n = blockIdx.x*256 + t;
        int g = gt[n];
        const float* uk = u + g*10;
        float bv = -1e30f; int idx = 0;
        #pragma unroll
        for (int m = 0; m < 10; ++m) {
            float pm = expv[(size_t)n*12 + m] * uk[m];
            if (pm > bv) { bv = pm; idx = m; }
        }
        ptarget[n] = (float)(idx + 10*g);
    }
    int wid = blockIdx.x*4 + (t >> 6);
    int lane = t & 63;
    int cnt = *ccnt; if (cnt > CCAP) cnt = CCAP;
    for (int i = wid; i < cnt; i += 4096) {
        int n = cidx[i];
        float x0 = feat[(size_t)n*128 + lane], x1 = feat[(size_t)n*128 + 64 + lane];
        float s = x0 + x1;
        #pragma unroll
        for (int off = 32; off > 0; off >>= 1) s += __shfl_xor(s, off);
        float mean = s * (1.f/128.f);
        float d0 = x0 - mean, d1 = x1 - mean;
        float s2 = d0*d0 + d1*d1;
        #pragma unroll
        for (int off = 32; off > 0; off >>= 1) s2 += __shfl_xor(s2, off);
        float rstd = rsqrtf(s2 * (1.f/128.f) + LNEPS);
        float y0 = d0*rstd*fg[lane] + fb[lane];
        float y1 = d1*rstd*fg[64+lane] + fb[64+lane];
        float s3 = y0*y0 + y1*y1;
        #pragma unroll
        for (int off = 32; off > 0; off >>= 1) s3 += __shfl_xor(s3, off);
        float rl2 = 1.f / fmaxf(sqrtf(s3), 1e-12f);
        float c0 = y0*rl2, c1 = y1*rl2;
        int g = gt[n];
        const float* uk = u + g*10;
        float bv = -1e30f; int idx = 0;
        #pragma unroll
        for (int m = 0; m < 10; ++m) {
            float pm = expv[(size_t)n*12 + m] * uk[m];
            if (pm > bv) { bv = pm; idx = m; }
        }
        float* frow = facc + (size_t)(g*10+idx)*128;
        atomicAdd(&frow[lane], c0);
        atomicAdd(&frow[64+lane], c1);
        if (lane == 0) atomicAdd(&ncount[g*10+idx], 1.f);
    }
}

// ---- momentum update + renormalize prototypes
__global__ __launch_bounds__(64) void k_proto_update(
    const float* __restrict__ facc, const float* __restrict__ ncount,
    const float* __restrict__ pn, float* __restrict__ outp)
{
    const float OMG = (float)(1.0 - 0.99);
    int j = blockIdx.x, l = threadIdx.x;
    float f0 = facc[(size_t)j*128+l], f1 = facc[(size_t)j*128+64+l];
    float ss = f0*f0 + f1*f1;
    #pragma unroll
    for (int off = 32; off > 0; off >>= 1) ss += __shfl_xor(ss, off);
    float fl2 = fmaxf(sqrtf(ss), 1e-12f);
    float fn0 = f0/fl2, fn1 = f1/fl2;
    float p0 = pn[(size_t)j*128+l], p1 = pn[(size_t)j*128+64+l];
    float u0 = 0.99f*p0 + OMG*fn0, u1 = 0.99f*p1 + OMG*fn1;
    bool ok = ncount[j] > 0.f;
    float s0 = ok ? u0 : p0, s1 = ok ? u1 : p1;
    float ss2 = s0*s0 + s1*s1;
    #pragma unroll
    for (int off = 32; off > 0; off >>= 1) ss2 += __shfl_xor(ss2, off);
    float l2 = fmaxf(sqrtf(ss2), 1e-12f);
    outp[(size_t)j*128+l]      = s0/l2;
    outp[(size_t)j*128+64+l]   = s1/l2;
}

extern "C" void kernel_launch(void* const* d_in, const int* in_sizes, int n_in,
                              void* d_out, int out_size, void* d_ws, size_t ws_size,
                              hipStream_t stream)
{
    const float* feat   = (const float*)d_in[0];
    const int*   gt     = (const int*)  d_in[1];
    const float* protos = (const float*)d_in[2];
    const float* fg     = (const float*)d_in[3];
    const float* fb     = (const float*)d_in[4];
    const float* mg     = (const float*)d_in[5];
    const float* mb     = (const float*)d_in[6];

    float* out      = (float*)d_out;
    float* out_seg  = out;
    float* plog     = out + (size_t)NPTS*20;
    float* ptarget  = out + (size_t)NPTS*220;
    float* newp     = out + (size_t)NPTS*221;

    float* ws   = (float*)d_ws;
    float* pn   = ws + WS_PN;
    _Float16* phi = (_Float16*)(ws + WS_PHI);
    _Float16* plo = (_Float16*)(ws + WS_PLO);
    float* facc = ws + WS_F;
    float* ncnt = ws + WS_NCOUNT;
    int*   ccnt = (int*)(ws + WS_CCNT);
    int*   tix  = ccnt + 1;                 // tix[0] = fused, tix[1..3] = row iters
    float* uh   = ws + WS_UH;
    float* sk   = ws + WS_SK;
    float* Bc   = ws + WS_BC;
    float* psb  = ws + WS_PSB;
    float* pr   = ws + WS_PR;
    float* expv = ws + WS_EXPV;
    int*   cidx = (int*)(ws + WS_CIDX);

    // zero facc + ncount + ccnt + tickets (contiguous)
    hipMemsetAsync(facc, 0, (25600 + 200 + 8)*sizeof(float), stream);
    hipLaunchKernelGGL(k_norm_protos, dim3(208), dim3(64), 0, stream, protos, pn, phi, plo);
    hipLaunchKernelGGL(k_fused, dim3(256), dim3(512), 0, stream,
                       feat, gt, phi, plo, fg, fb, mg, mb, out_seg, plog, expv, psb,
                       cidx, ccnt, tix + 0, sk, Bc);
    for (int it = 1; it <= 3; ++it)
        hipLaunchKernelGGL(k_row, dim3(1024), dim3(256), 0, stream,
                           it, gt, expv, uh, sk, Bc, pr, tix + it);
    hipLaunchKernelGGL(k_post, dim3(1024), dim3(256), 0, stream,
                       gt, expv, uh + 400, cidx, ccnt, feat, fg, fb, ptarget, facc, ncnt);
    hipLaunchKernelGGL(k_proto_update, dim3(200), dim3(64), 0, stream, facc, ncnt, pn, newp);
}

// Round 9
// 297.370 us; speedup vs baseline: 2.7035x; 2.7035x over previous
//
#include <hip/hip_runtime.h>
#include <hip/hip_bf16.h>

#define NPTS 262144
#define DIM  128
#define KC   20
#define MP   10
#define LNEPS 1e-5f
#define EPSI  0.05f
#define CCAP  65536

typedef _Float16 half8 __attribute__((ext_vector_type(8)));
typedef float f32x4 __attribute__((ext_vector_type(4)));

union H8U4 { half8 h; uint4 u; };

// workspace layout (float offsets)
#define WS_PN     0          // 25600 normalized protos f32
#define WS_PHI    25600      // 14336 floats (224x128 f16 hi, rows 200..223 zero)
#define WS_PLO    39936      // 14336 floats (f16 lo)
#define WS_F      54272      // 25600 f accumulator
#define WS_NCOUNT 79872      // 200
#define WS_CCNT   80072      // 8 ints (ccnt + pad)
#define WS_UH     80080      // 600 u history (3 x 200)
#define WS_SK     80680      // 20
#define WS_BC     80700      // 20
#define WS_PSB    80720      // 40*2048 partials
#define WS_PR     162640     // 200*1024 row-sum partials
#define WS_EXPV   367440     // N*12 (10 + 2 pad)
#define WS_CIDX   3513168    // 65536 ints
// total 3578704 floats = 14.3 MB

#define MFMA_(b_, a_, c_) __builtin_amdgcn_mfma_f32_16x16x32_f16(b_, a_, c_, 0, 0, 0)

__device__ __forceinline__ half8 lds_h8(const uint4* p) {
    return *reinterpret_cast<const half8*>(p);
}

// ---- normalize prototypes, emit f32 + f16 hi/lo (rows 200..223 zero-padded)
__global__ __launch_bounds__(64) void k_norm_protos(
    const float* __restrict__ pr, float* __restrict__ pn,
    _Float16* __restrict__ phi, _Float16* __restrict__ plo)
{
    int j = blockIdx.x, l = threadIdx.x;
    if (j < 200) {
        float x0 = pr[(size_t)j*128 + l], x1 = pr[(size_t)j*128 + 64 + l];
        float ss = x0*x0 + x1*x1;
        #pragma unroll
        for (int off = 32; off > 0; off >>= 1) ss += __shfl_xor(ss, off);
        float dn = fmaxf(sqrtf(ss), 1e-12f);
        float y0 = x0/dn, y1 = x1/dn;
        pn[(size_t)j*128 + l]      = y0;
        pn[(size_t)j*128 + 64 + l] = y1;
        _Float16 h0 = (_Float16)y0, h1 = (_Float16)y1;
        phi[(size_t)j*128 + l]      = h0;
        phi[(size_t)j*128 + 64 + l] = h1;
        plo[(size_t)j*128 + l]      = (_Float16)(y0 - (float)h0);
        plo[(size_t)j*128 + 64 + l] = (_Float16)(y1 - (float)h1);
    } else {
        phi[(size_t)j*128 + l] = (_Float16)0.f;  phi[(size_t)j*128 + 64 + l] = (_Float16)0.f;
        plo[(size_t)j*128 + l] = (_Float16)0.f;  plo[(size_t)j*128 + 64 + l] = (_Float16)0.f;
    }
}

// ---- main kernel: 2048 blocks x 256 thr (4 waves), 128 pts/block.
//  A: direct per-lane global fragment loads + shfl LN (no LDS, no barriers).
//  B: double-buffered 32-col stages x7 (32 KB LDS), one barrier per stage.
//  Epilogue in-kernel: 4 passes of 32 pts through the dead B region.
__global__ __launch_bounds__(256, 2) void k_main(
    const float* __restrict__ feat, const int* __restrict__ gt,
    const _Float16* __restrict__ phi, const _Float16* __restrict__ plo,
    const float* __restrict__ fg, const float* __restrict__ fb,
    const float* __restrict__ mg, const float* __restrict__ mb,
    float* __restrict__ out_seg, float* __restrict__ plog,
    float* __restrict__ expv, float* __restrict__ psb,
    int* __restrict__ cidx, int* __restrict__ ccnt)
{
    __shared__ __align__(16) char ldsb[32768];   // B dbuf; reused as epi [32][210]
    __shared__ float sumS[128];
    __shared__ int   gtS[128];
    __shared__ float part[320];
    uint4* bbuf = (uint4*)ldsb;                  // buf b at +b*1024 u4; hi +0, lo +512
    float* epi  = (float*)ldsb;

    const int t = threadIdx.x, blk = blockIdx.x;
    const int w = t >> 6, lane = t & 63;
    const int l15 = lane & 15, l4 = lane >> 4;
    const int pbase = blk * 128;

    const uint4* phi4 = (const uint4*)phi;
    const uint4* plo4 = (const uint4*)plo;
    // staging geometry: per stage 32 rows x 16 u4 (hi) + same (lo); 2 rows/thread
    const int sr0 = t >> 4, sr1 = 16 + (t >> 4), sc = t & 15;
    const int d0 = sr0*16 + (sc ^ sr0);          // sr0 in 0..15
    const int d1 = sr1*16 + (sc ^ (sr1 & 15));

    uint4 sh[2], slr[2];
    // prologue: issue stage-0 B loads
    sh[0]  = phi4[(size_t)sr0*16 + sc];  sh[1]  = phi4[(size_t)sr1*16 + sc];
    slr[0] = plo4[(size_t)sr0*16 + sc];  slr[1] = plo4[(size_t)sr1*16 + sc];

    // ---- A direct loads in fragment layout (in flight with B0)
    const float4* gfeat = (const float4*)feat;
    float4 A[2][4][2];
    #pragma unroll
    for (int mt = 0; mt < 2; ++mt) {
        size_t rb = (size_t)(pbase + w*32 + mt*16 + l15) * 32;
        #pragma unroll
        for (int kst = 0; kst < 4; ++kst)
            #pragma unroll
            for (int h = 0; h < 2; ++h)
                A[mt][kst][h] = gfeat[rb + kst*8 + l4*2 + h];
    }
    float4 G[4][2], Bb[4][2];
    {
        const float4* fg4 = (const float4*)fg;
        const float4* fb4 = (const float4*)fb;
        #pragma unroll
        for (int kst = 0; kst < 4; ++kst)
            #pragma unroll
            for (int h = 0; h < 2; ++h) {
                G[kst][h]  = fg4[kst*8 + l4*2 + h];
                Bb[kst][h] = fb4[kst*8 + l4*2 + h];
            }
    }

    // ---- LN + l2n per mt (4-lane group reduce over lanes {l15,+16,+32,+48})
    half8 fah[2][4], fal[2][4];
    #pragma unroll
    for (int mt = 0; mt < 2; ++mt) {
        float s0 = 0.f;
        #pragma unroll
        for (int kst = 0; kst < 4; ++kst)
            #pragma unroll
            for (int h = 0; h < 2; ++h) {
                float4 v = A[mt][kst][h];
                s0 += v.x + v.y + v.z + v.w;
            }
        s0 += __shfl_xor(s0, 16); s0 += __shfl_xor(s0, 32);
        float mean = s0 * (1.f/128.f);
        float s1 = 0.f;
        #pragma unroll
        for (int kst = 0; kst < 4; ++kst)
            #pragma unroll
            for (int h = 0; h < 2; ++h) {
                float4 v = A[mt][kst][h];
                float a = v.x-mean, b = v.y-mean, c = v.z-mean, d = v.w-mean;
                s1 += a*a + b*b + c*c + d*d;
            }
        s1 += __shfl_xor(s1, 16); s1 += __shfl_xor(s1, 32);
        float rstd = rsqrtf(s1 * (1.f/128.f) + LNEPS);
        float s2 = 0.f;
        #pragma unroll
        for (int kst = 0; kst < 4; ++kst)
            #pragma unroll
            for (int h = 0; h < 2; ++h) {
                float4 v = A[mt][kst][h];
                float4 g = G[kst][h], bb = Bb[kst][h];
                v.x = (v.x-mean)*rstd*g.x + bb.x;
                v.y = (v.y-mean)*rstd*g.y + bb.y;
                v.z = (v.z-mean)*rstd*g.z + bb.z;
                v.w = (v.w-mean)*rstd*g.w + bb.w;
                A[mt][kst][h] = v;
                s2 += v.x*v.x + v.y*v.y + v.z*v.z + v.w*v.w;
            }
        s2 += __shfl_xor(s2, 16); s2 += __shfl_xor(s2, 32);
        float rl2 = 1.f / fmaxf(sqrtf(s2), 1e-12f);
        #pragma unroll
        for (int kst = 0; kst < 4; ++kst) {
            float4 va = A[mt][kst][0], vb = A[mt][kst][1];
            va.x*=rl2; va.y*=rl2; va.z*=rl2; va.w*=rl2;
            vb.x*=rl2; vb.y*=rl2; vb.z*=rl2; vb.w*=rl2;
            H8U4 h, lo;
            h.h[0]=(_Float16)va.x; h.h[1]=(_Float16)va.y; h.h[2]=(_Float16)va.z; h.h[3]=(_Float16)va.w;
            h.h[4]=(_Float16)vb.x; h.h[5]=(_Float16)vb.y; h.h[6]=(_Float16)vb.z; h.h[7]=(_Float16)vb.w;
            lo.h[0]=(_Float16)(va.x-(float)h.h[0]); lo.h[1]=(_Float16)(va.y-(float)h.h[1]);
            lo.h[2]=(_Float16)(va.z-(float)h.h[2]); lo.h[3]=(_Float16)(va.w-(float)h.h[3]);
            lo.h[4]=(_Float16)(vb.x-(float)h.h[4]); lo.h[5]=(_Float16)(vb.y-(float)h.h[5]);
            lo.h[6]=(_Float16)(vb.z-(float)h.h[6]); lo.h[7]=(_Float16)(vb.w-(float)h.h[7]);
            fah[mt][kst] = h.h;
            fal[mt][kst] = lo.h;
        }
    }

    // write buf0 (B0 arrived during LN), prefetch stage 1
    bbuf[d0] = sh[0]; bbuf[d1] = sh[1]; bbuf[512+d0] = slr[0]; bbuf[512+d1] = slr[1];
    sh[0]  = phi4[(size_t)(32+sr0)*16 + sc];  sh[1]  = phi4[(size_t)(32+sr1)*16 + sc];
    slr[0] = plo4[(size_t)(32+sr0)*16 + sc];  slr[1] = plo4[(size_t)(32+sr1)*16 + sc];

    f32x4 acc[2][13];
    #pragma unroll
    for (int mt = 0; mt < 2; ++mt)
        #pragma unroll
        for (int nt = 0; nt < 13; ++nt)
            acc[mt][nt] = (f32x4){0.f,0.f,0.f,0.f};

    // ---- staged GEMM: one barrier per stage, MFMA interleaved over 4 acc chains
    #pragma unroll
    for (int s = 0; s < 7; ++s) {
        __syncthreads();
        const uint4* bb = bbuf + (s & 1)*1024;
        if (s < 6) {
            #pragma unroll
            for (int kst = 0; kst < 4; ++kst) {
                const int slz = (kst*4 + l4) ^ l15;
                half8 b0h = lds_h8(bb + l15*16 + slz);
                half8 b0l = lds_h8(bb + 512 + l15*16 + slz);
                half8 b1h = lds_h8(bb + (16+l15)*16 + slz);
                half8 b1l = lds_h8(bb + 512 + (16+l15)*16 + slz);
                acc[0][2*s]   = MFMA_(b0h, fah[0][kst], acc[0][2*s]);
                acc[1][2*s]   = MFMA_(b0h, fah[1][kst], acc[1][2*s]);
                acc[0][2*s+1] = MFMA_(b1h, fah[0][kst], acc[0][2*s+1]);
                acc[1][2*s+1] = MFMA_(b1h, fah[1][kst], acc[1][2*s+1]);
                acc[0][2*s]   = MFMA_(b0h, fal[0][kst], acc[0][2*s]);
                acc[1][2*s]   = MFMA_(b0h, fal[1][kst], acc[1][2*s]);
                acc[0][2*s+1] = MFMA_(b1h, fal[0][kst], acc[0][2*s+1]);
                acc[1][2*s+1] = MFMA_(b1h, fal[1][kst], acc[1][2*s+1]);
                acc[0][2*s]   = MFMA_(b0l, fah[0][kst], acc[0][2*s]);
                acc[1][2*s]   = MFMA_(b0l, fah[1][kst], acc[1][2*s]);
                acc[0][2*s+1] = MFMA_(b1l, fah[0][kst], acc[0][2*s+1]);
                acc[1][2*s+1] = MFMA_(b1l, fah[1][kst], acc[1][2*s+1]);
                acc[0][2*s]   = MFMA_(b0l, fal[0][kst], acc[0][2*s]);
                acc[1][2*s]   = MFMA_(b0l, fal[1][kst], acc[1][2*s]);
                acc[0][2*s+1] = MFMA_(b1l, fal[0][kst], acc[0][2*s+1]);
                acc[1][2*s+1] = MFMA_(b1l, fal[1][kst], acc[1][2*s+1]);
            }
            uint4* bp = bbuf + ((s+1) & 1)*1024;
            bp[d0] = sh[0]; bp[d1] = sh[1]; bp[512+d0] = slr[0]; bp[512+d1] = slr[1];
            if (s < 5) {
                sh[0]  = phi4[(size_t)((s+2)*32 + sr0)*16 + sc];
                sh[1]  = phi4[(size_t)((s+2)*32 + sr1)*16 + sc];
                slr[0] = plo4[(size_t)((s+2)*32 + sr0)*16 + sc];
                slr[1] = plo4[(size_t)((s+2)*32 + sr1)*16 + sc];
            }
        } else {
            #pragma unroll
            for (int kst = 0; kst < 4; ++kst) {
                const int slz = (kst*4 + l4) ^ l15;
                half8 b0h = lds_h8(bb + l15*16 + slz);
                half8 b0l = lds_h8(bb + 512 + l15*16 + slz);
                acc[0][12] = MFMA_(b0h, fah[0][kst], acc[0][12]);
                acc[1][12] = MFMA_(b0h, fah[1][kst], acc[1][12]);
                acc[0][12] = MFMA_(b0h, fal[0][kst], acc[0][12]);
                acc[1][12] = MFMA_(b0h, fal[1][kst], acc[1][12]);
                acc[0][12] = MFMA_(b0l, fah[0][kst], acc[0][12]);
                acc[1][12] = MFMA_(b0l, fah[1][kst], acc[1][12]);
                acc[0][12] = MFMA_(b0l, fal[0][kst], acc[0][12]);
                acc[1][12] = MFMA_(b0l, fal[1][kst], acc[1][12]);
            }
        }
    }

    // ---- plog float4 stores (lane l15 = point, cols nt*16 + l4*4 + {0..3})
    #pragma unroll
    for (int mt = 0; mt < 2; ++mt)
        #pragma unroll
        for (int nt = 0; nt < 13; ++nt)
            if (nt < 12 || l4 < 2) {
                float4 sv;
                sv.x = acc[mt][nt][0]; sv.y = acc[mt][nt][1];
                sv.z = acc[mt][nt][2]; sv.w = acc[mt][nt][3];
                *reinterpret_cast<float4*>(
                    &plog[(size_t)(pbase + w*32 + mt*16 + l15)*200 + nt*16 + l4*4]) = sv;
            }

    // ---- epilogue: 4 passes of 32 points via dead B region ([32][210])
    #pragma unroll 1
    for (int p = 0; p < 4; ++p) {
        __syncthreads();   // prior pass reads / stage-6 LDS reads complete
        if (w == p) {
            #pragma unroll
            for (int mt = 0; mt < 2; ++mt)
                #pragma unroll
                for (int nt = 0; nt < 13; ++nt)
                    if (nt < 12 || l4 < 2) {
                        float4 sv;
                        sv.x = acc[mt][nt][0]; sv.y = acc[mt][nt][1];
                        sv.z = acc[mt][nt][2]; sv.w = acc[mt][nt][3];
                        *reinterpret_cast<float4*>(
                            &epi[(mt*16 + l15)*210 + nt*16 + l4*4]) = sv;
                    }
        }
        __syncthreads();
        if (t < 128) {
            const int q = t >> 2, sub = t & 3;
            const int n = pbase + p*32 + q;
            float ml[5];
            #pragma unroll
            for (int kk = 0; kk < 5; ++kk) {
                int k = sub*5 + kk;
                float mx = epi[q*210 + k*10];
                #pragma unroll
                for (int m = 1; m < 10; ++m) mx = fmaxf(mx, epi[q*210 + k*10 + m]);
                ml[kk] = mx;
            }
            float s0 = ml[0]+ml[1]+ml[2]+ml[3]+ml[4];
            s0 += __shfl_xor(s0,1); s0 += __shfl_xor(s0,2);
            float mean = s0 / 20.f;
            float s1 = 0.f;
            #pragma unroll
            for (int kk = 0; kk < 5; ++kk) { float d = ml[kk]-mean; s1 += d*d; }
            s1 += __shfl_xor(s1,1); s1 += __shfl_xor(s1,2);
            float rstd = rsqrtf(s1 / 20.f + LNEPS);
            float bv = -1e30f; int bk = 0;
            #pragma unroll
            for (int kk = 0; kk < 5; ++kk) {
                int k = sub*5 + kk;
                float y = (ml[kk]-mean)*rstd*mg[k] + mb[k];
                out_seg[(size_t)n*20 + k] = y;
                if (y > bv) { bv = y; bk = k; }
            }
            #pragma unroll
            for (int off = 1; off <= 2; off <<= 1) {   // first-max-wins merge
                float ov = __shfl_xor(bv, off);
                int   ok = __shfl_xor(bk, off);
                if (ov > bv || (ov == bv && ok < bk)) { bv = ov; bk = ok; }
            }
            int g = gt[n];
            if (sub == 0) {
                if (bk == g) {
                    int slot = atomicAdd(ccnt, 1);
                    if (slot < CCAP) cidx[slot] = n;
                }
                float se = 0.f;
                #pragma unroll
                for (int m = 0; m < 10; ++m) {
                    float e = expf(epi[q*210 + g*10 + m] / EPSI);
                    expv[(size_t)n*12 + m] = e;
                    se += e;
                }
                sumS[p*32 + q] = se;
                gtS[p*32 + q]  = g;
            }
        }
    }

    // ---- deterministic per-block class partials over 128 points
    __syncthreads();
    if (t < 160) {
        int c = t >> 3, o = t & 7;
        float cnt = 0.f, sm = 0.f;
        for (int i = o*16; i < o*16 + 16; ++i)
            if (gtS[i] == c) { cnt += 1.f; sm += sumS[i]; }
        part[t] = cnt; part[160 + t] = sm;
    }
    __syncthreads();
    if (t < 20) {
        float cnt = 0.f, sm = 0.f;
        #pragma unroll
        for (int o = 0; o < 8; ++o) { cnt += part[t*8+o]; sm += part[160 + t*8+o]; }
        psb[(size_t)t*2048 + blk]      = cnt;
        psb[(size_t)(20+t)*2048 + blk] = sm;
    }
}

// ---- reduce class partials -> Bc, sk (deterministic tree)
__global__ __launch_bounds__(256) void k_reduce_sB(
    const float* __restrict__ psb, float* __restrict__ sk, float* __restrict__ Bc)
{
    __shared__ float red[256];
    int t = threadIdx.x, rrow = blockIdx.x;
    float s = 0.f;
    #pragma unroll
    for (int i = 0; i < 8; ++i) s += psb[(size_t)rrow*2048 + i*256 + t];
    red[t] = s; __syncthreads();
    for (int off = 128; off > 0; off >>= 1) { if (t < off) red[t] += red[t+off]; __syncthreads(); }
    if (t == 0) { if (rrow < 20) Bc[rrow] = red[0]; else sk[rrow-20] = red[0]; }
}

// ---- sinkhorn row pass with fused v-chain (iter = 1,2,3)
__global__ __launch_bounds__(256) void k_row(int iter,
    const int* __restrict__ gt, const float* __restrict__ expv,
    const float* __restrict__ uh, const float* __restrict__ sk,
    const float* __restrict__ Bc, float* __restrict__ pr)
{
    __shared__ float prodS[2560];
    __shared__ int gtS[256];
    int t = threadIdx.x, b = blockIdx.x;
    int n = b*256 + t;
    int g = gt[n];
    float e[10];
    {
        const float4* e4 = (const float4*)(expv + (size_t)n*12);
        float4 ea = e4[0], eb = e4[1], ec = e4[2];
        e[0]=ea.x; e[1]=ea.y; e[2]=ea.z; e[3]=ea.w;
        e[4]=eb.x; e[5]=eb.y; e[6]=eb.z; e[7]=eb.w;
        e[8]=ec.x; e[9]=ec.y;
    }
    float skg = sk[g];
    float v = (skg > 0.f) ? 1.f/skg : 1.f;
    float B = Bc[g];
    float Bs = (B > 0.f) ? B : 1.f;
    for (int c = 1; c < iter; ++c) {
        const float* uc = uh + (c-1)*200 + g*10;
        float sc = 0.f;
        #pragma unroll
        for (int m = 0; m < 10; ++m) sc += e[m]*uc[m];
        v = (sc > 0.f) ? 1.f/(Bs*sc) : v/Bs;
    }
    #pragma unroll
    for (int m = 0; m < 10; ++m) prodS[t*10+m] = e[m]*v;
    gtS[t] = g;
    __syncthreads();
    if (t < 200) {
        int kk = t / 10, mm = t % 10;
        float acc = 0.f;
        for (int i = 0; i < 256; ++i)
            if (gtS[i] == kk) acc += prodS[i*10+mm];
        pr[(size_t)t*1024 + b] = acc;
    }
}

// ---- row partials -> u_hist[iter] (faithful rs>0 guard), deterministic
__global__ __launch_bounds__(256) void k_reduce_u(int iter,
    const float* __restrict__ pr, float* __restrict__ uh)
{
    __shared__ float red[256];
    int t = threadIdx.x, j = blockIdx.x;
    float s = 0.f;
    #pragma unroll
    for (int i = 0; i < 4; ++i) s += pr[(size_t)j*1024 + i*256 + t];
    red[t] = s; __syncthreads();
    for (int off = 128; off > 0; off >>= 1) { if (t < off) red[t] += red[t+off]; __syncthreads(); }
    if (t == 0) {
        float S = red[0];
        float uprev = (iter == 1) ? 1.f : uh[(iter-2)*200 + j];
        uh[(iter-1)*200 + j] = (S > 0.f) ? 1.f/(10.f*S) : uprev*0.1f;
    }
}

// ---- assignment + f/ncount accumulation (no fences; kernel-boundary coherence)
__global__ __launch_bounds__(256) void k_post(
    const int* __restrict__ gt, const float* __restrict__ expv,
    const float* __restrict__ u,
    const int* __restrict__ cidx, const int* __restrict__ ccnt,
    const float* __restrict__ feat, const float* __restrict__ fg,
    const float* __restrict__ fb,
    float* __restrict__ ptarget, float* __restrict__ facc,
    float* __restrict__ ncount)
{
    int t = threadIdx.x;
    {
        int n = blockIdx.x*256 + t;
        int g = gt[n];
        const float* uk = u + g*10;
        float bv = -1e30f; int idx = 0;
        #pragma unroll
        for (int m = 0; m < 10; ++m) {
            float pm = expv[(size_t)n*12 + m] * uk[m];
            if (pm > bv) { bv = pm; idx = m; }
        }
        ptarget[n] = (float)(idx + 10*g);
    }
    int wid = blockIdx.x*4 + (t >> 6);
    int lane = t & 63;
    int cnt = *ccnt; if (cnt > CCAP) cnt = CCAP;
    for (int i = wid; i < cnt; i += 4096) {
        int n = cidx[i];
        float x0 = feat[(size_t)n*128 + lane], x1 = feat[(size_t)n*128 + 64 + lane];
        float s = x0 + x1;
        #pragma unroll
        for (int off = 32; off > 0; off >>= 1) s += __shfl_xor(s, off);
        float mean = s * (1.f/128.f);
        float d0 = x0 - mean, d1 = x1 - mean;
        float s2 = d0*d0 + d1*d1;
        #pragma unroll
        for (int off = 32; off > 0; off >>= 1) s2 += __shfl_xor(s2, off);
        float rstd = rsqrtf(s2 * (1.f/128.f) + LNEPS);
        float y0 = d0*rstd*fg[lane] + fb[lane];
        float y1 = d1*rstd*fg[64+lane] + fb[64+lane];
        float s3 = y0*y0 + y1*y1;
        #pragma unroll
        for (int off = 32; off > 0; off >>= 1) s3 += __shfl_xor(s3, off);
        float rl2 = 1.f / fmaxf(sqrtf(s3), 1e-12f);
        float c0 = y0*rl2, c1 = y1*rl2;
        int g = gt[n];
        const float* uk = u + g*10;
        float bv = -1e30f; int idx = 0;
        #pragma unroll
        for (int m = 0; m < 10; ++m) {
            float pm = expv[(size_t)n*12 + m] * uk[m];
            if (pm > bv) { bv = pm; idx = m; }
        }
        float* frow = facc + (size_t)(g*10+idx)*128;
        atomicAdd(&frow[lane], c0);
        atomicAdd(&frow[64+lane], c1);
        if (lane == 0) atomicAdd(&ncount[g*10+idx], 1.f);
    }
}

// ---- momentum update + renormalize prototypes
__global__ __launch_bounds__(64) void k_proto_update(
    const float* __restrict__ facc, const float* __restrict__ ncount,
    const float* __restrict__ pn, float* __restrict__ outp)
{
    const float OMG = (float)(1.0 - 0.99);
    int j = blockIdx.x, l = threadIdx.x;
    float f0 = facc[(size_t)j*128+l], f1 = facc[(size_t)j*128+64+l];
    float ss = f0*f0 + f1*f1;
    #pragma unroll
    for (int off = 32; off > 0; off >>= 1) ss += __shfl_xor(ss, off);
    float fl2 = fmaxf(sqrtf(ss), 1e-12f);
    float fn0 = f0/fl2, fn1 = f1/fl2;
    float p0 = pn[(size_t)j*128+l], p1 = pn[(size_t)j*128+64+l];
    float u0 = 0.99f*p0 + OMG*fn0, u1 = 0.99f*p1 + OMG*fn1;
    bool ok = ncount[j] > 0.f;
    float s0 = ok ? u0 : p0, s1 = ok ? u1 : p1;
    float ss2 = s0*s0 + s1*s1;
    #pragma unroll
    for (int off = 32; off > 0; off >>= 1) ss2 += __shfl_xor(ss2, off);
    float l2 = fmaxf(sqrtf(ss2), 1e-12f);
    outp[(size_t)j*128+l]      = s0/l2;
    outp[(size_t)j*128+64+l]   = s1/l2;
}

extern "C" void kernel_launch(void* const* d_in, const int* in_sizes, int n_in,
                              void* d_out, int out_size, void* d_ws, size_t ws_size,
                              hipStream_t stream)
{
    const float* feat   = (const float*)d_in[0];
    const int*   gt     = (const int*)  d_in[1];
    const float* protos = (const float*)d_in[2];
    const float* fg     = (const float*)d_in[3];
    const float* fb     = (const float*)d_in[4];
    const float* mg     = (const float*)d_in[5];
    const float* mb     = (const float*)d_in[6];

    float* out      = (float*)d_out;
    float* out_seg  = out;
    float* plog     = out + (size_t)NPTS*20;
    float* ptarget  = out + (size_t)NPTS*220;
    float* newp     = out + (size_t)NPTS*221;

    float* ws   = (float*)d_ws;
    float* pn   = ws + WS_PN;
    _Float16* phi = (_Float16*)(ws + WS_PHI);
    _Float16* plo = (_Float16*)(ws + WS_PLO);
    float* facc = ws + WS_F;
    float* ncnt = ws + WS_NCOUNT;
    int*   ccnt = (int*)(ws + WS_CCNT);
    float* uh   = ws + WS_UH;
    float* sk   = ws + WS_SK;
    float* Bc   = ws + WS_BC;
    float* psb  = ws + WS_PSB;
    float* pr   = ws + WS_PR;
    float* expv = ws + WS_EXPV;
    int*   cidx = (int*)(ws + WS_CIDX);

    // zero facc + ncount + ccnt (contiguous)
    hipMemsetAsync(facc, 0, (25600 + 200 + 8)*sizeof(float), stream);
    hipLaunchKernelGGL(k_norm_protos, dim3(224), dim3(64), 0, stream, protos, pn, phi, plo);
    hipLaunchKernelGGL(k_main, dim3(2048), dim3(256), 0, stream,
                       feat, gt, phi, plo, fg, fb, mg, mb, out_seg, plog, expv, psb,
                       cidx, ccnt);
    hipLaunchKernelGGL(k_reduce_sB, dim3(40), dim3(256), 0, stream, psb, sk, Bc);
    for (int it = 1; it <= 3; ++it) {
        hipLaunchKernelGGL(k_row, dim3(1024), dim3(256), 0, stream, it, gt, expv, uh, sk, Bc, pr);
        hipLaunchKernelGGL(k_reduce_u, dim3(200), dim3(256), 0, stream, it, pr, uh);
    }
    hipLaunchKernelGGL(k_post, dim3(1024), dim3(256), 0, stream,
                       gt, expv, uh + 400, cidx, ccnt, feat, fg, fb, ptarget, facc, ncnt);
    hipLaunchKernelGGL(k_proto_update, dim3(200), dim3(64), 0, stream, facc, ncnt, pn, newp);
}

// Round 10
// 273.407 us; speedup vs baseline: 2.9405x; 1.0876x over previous
//
#include <hip/hip_runtime.h>
#include <hip/hip_bf16.h>

#define NPTS 262144
#define DIM  128
#define KC   20
#define MP   10
#define LNEPS 1e-5f
#define EPSI  0.05f
#define CCAP  65536

typedef _Float16 half8 __attribute__((ext_vector_type(8)));
typedef float f32x4 __attribute__((ext_vector_type(4)));

union H8U4 { half8 h; uint4 u; };

// workspace layout (float offsets)
#define WS_PN     0          // 25600 normalized protos f32
#define WS_PHI    25600      // 14336 floats (224x128 f16 hi, PRE-SWIZZLED, rows 200..223 zero)
#define WS_PLO    39936      // 14336 floats (f16 lo, PRE-SWIZZLED)
#define WS_F      54272      // 25600 f accumulator
#define WS_NCOUNT 79872      // 200
#define WS_CCNT   80072      // 8 ints (ccnt + pad)
#define WS_UH     80080      // 600 u history (3 x 200)
#define WS_SK     80680      // 20
#define WS_BC     80700      // 20
#define WS_PSB    80720      // 40*2048 partials
#define WS_PR     162640     // 200*1024 row-sum partials
#define WS_EXPV   367440     // N*12 (10 + 2 pad)
#define WS_CIDX   3513168    // 65536 ints
// total 3578704 floats = 14.3 MB

#define MFMA_(b_, a_, c_) __builtin_amdgcn_mfma_f32_16x16x32_f16(b_, a_, c_, 0, 0, 0)

__device__ __forceinline__ half8 lds_h8(const uint4* p) {
    return *reinterpret_cast<const half8*>(p);
}

// async global->LDS, 16B per lane; LDS dest = wave-uniform base + lane*16
__device__ __forceinline__ void gload_lds16(const uint4* g, uint4* l) {
    __builtin_amdgcn_global_load_lds(
        (const __attribute__((address_space(1))) void*)(g),
        (__attribute__((address_space(3))) void*)(l), 16, 0, 0);
}

// ---- normalize prototypes; emit f32 (pn) + PRE-SWIZZLED f16 hi/lo.
//  Swizzle (u4-granular): row j, u4-slot s -> slot s ^ (j&15). So a LINEAR
//  global_load_lds of a 32-row stage lands in LDS exactly in the layout the
//  MFMA reader expects (LDS[row][x] = orig[row][x ^ (row&15)]).
__global__ __launch_bounds__(64) void k_norm_protos(
    const float* __restrict__ pr, float* __restrict__ pn,
    _Float16* __restrict__ phi, _Float16* __restrict__ plo)
{
    int j = blockIdx.x, l = threadIdx.x;
    const int jm = j & 15;
    const int s1 = l >> 3,       swz1 = (((s1 ^ jm) << 3) | (l & 7));
    const int s2 = 8 + (l >> 3), swz2 = (((s2 ^ jm) << 3) | (l & 7));
    if (j < 200) {
        float x0 = pr[(size_t)j*128 + l], x1 = pr[(size_t)j*128 + 64 + l];
        float ss = x0*x0 + x1*x1;
        #pragma unroll
        for (int off = 32; off > 0; off >>= 1) ss += __shfl_xor(ss, off);
        float dn = fmaxf(sqrtf(ss), 1e-12f);
        float y0 = x0/dn, y1 = x1/dn;
        pn[(size_t)j*128 + l]      = y0;
        pn[(size_t)j*128 + 64 + l] = y1;
        _Float16 h0 = (_Float16)y0, h1 = (_Float16)y1;
        phi[(size_t)j*128 + swz1] = h0;
        phi[(size_t)j*128 + swz2] = h1;
        plo[(size_t)j*128 + swz1] = (_Float16)(y0 - (float)h0);
        plo[(size_t)j*128 + swz2] = (_Float16)(y1 - (float)h1);
    } else {
        phi[(size_t)j*128 + swz1] = (_Float16)0.f;  phi[(size_t)j*128 + swz2] = (_Float16)0.f;
        plo[(size_t)j*128 + swz1] = (_Float16)0.f;  plo[(size_t)j*128 + swz2] = (_Float16)0.f;
    }
}

// ---- main kernel: 2048 blocks x 256 thr (4 waves), 128 pts/block.
//  A: direct per-lane global fragment loads + shfl LN (no LDS, no barriers).
//  B: global_load_lds, 3-deep buffers, loads issued at TOP of stage (full
//     MFMA-stage of latency cover before the barrier drain).
//  Epilogue from acc via dead-B LDS; plog stores LAST (no barrier after).
__global__ __launch_bounds__(256, 2) void k_main(
    const float* __restrict__ feat, const int* __restrict__ gt,
    const _Float16* __restrict__ phi, const _Float16* __restrict__ plo,
    const float* __restrict__ fg, const float* __restrict__ fb,
    const float* __restrict__ mg, const float* __restrict__ mb,
    float* __restrict__ out_seg, float* __restrict__ plog,
    float* __restrict__ expv, float* __restrict__ psb,
    int* __restrict__ cidx, int* __restrict__ ccnt)
{
    __shared__ __align__(16) char ldsb[49152];   // 3 x 16KB B buffers; epi reuse
    __shared__ float sumS[128];
    __shared__ int   gtS[128];
    __shared__ float part[320];
    uint4* bbuf = (uint4*)ldsb;                  // buf b at +b*1024 u4; hi +0, lo +512
    float* epi  = (float*)ldsb;                  // [32][210] after GEMM

    const int t = threadIdx.x, blk = blockIdx.x;
    const int w = t >> 6, lane = t & 63;
    const int l15 = lane & 15, l4 = lane >> 4;
    const int pbase = blk * 128;

    const uint4* phi4 = (const uint4*)phi;
    const uint4* plo4 = (const uint4*)plo;

    // issue B stage S into buffer BI (4 x 16B-per-lane async ops per thread-group)
#define STAGE_B(S, BI) do { \
        const uint4* gh = phi4 + (size_t)(S)*512 + (w*64 + lane); \
        const uint4* gl = plo4 + (size_t)(S)*512 + (w*64 + lane); \
        uint4* dh = bbuf + (BI)*1024 + w*64; \
        uint4* dl = bbuf + (BI)*1024 + 512 + w*64; \
        gload_lds16(gh,       dh); \
        gload_lds16(gh + 256, dh + 256); \
        gload_lds16(gl,       dl); \
        gload_lds16(gl + 256, dl + 256); \
    } while (0)

    // prologue: issue B0, B1 (in flight under A-load + LN)
    STAGE_B(0, 0);
    STAGE_B(1, 1);

    // ---- A direct loads in fragment layout
    const float4* gfeat = (const float4*)feat;
    float4 A[2][4][2];
    #pragma unroll
    for (int mt = 0; mt < 2; ++mt) {
        size_t rb = (size_t)(pbase + w*32 + mt*16 + l15) * 32;
        #pragma unroll
        for (int kst = 0; kst < 4; ++kst)
            #pragma unroll
            for (int h = 0; h < 2; ++h)
                A[mt][kst][h] = gfeat[rb + kst*8 + l4*2 + h];
    }
    float4 G[4][2], Bb[4][2];
    {
        const float4* fg4 = (const float4*)fg;
        const float4* fb4 = (const float4*)fb;
        #pragma unroll
        for (int kst = 0; kst < 4; ++kst)
            #pragma unroll
            for (int h = 0; h < 2; ++h) {
                G[kst][h]  = fg4[kst*8 + l4*2 + h];
                Bb[kst][h] = fb4[kst*8 + l4*2 + h];
            }
    }

    // ---- LN + l2n per mt (4-lane group reduce over lanes {l15,+16,+32,+48})
    half8 fah[2][4], fal[2][4];
    #pragma unroll
    for (int mt = 0; mt < 2; ++mt) {
        float s0 = 0.f;
        #pragma unroll
        for (int kst = 0; kst < 4; ++kst)
            #pragma unroll
            for (int h = 0; h < 2; ++h) {
                float4 v = A[mt][kst][h];
                s0 += v.x + v.y + v.z + v.w;
            }
        s0 += __shfl_xor(s0, 16); s0 += __shfl_xor(s0, 32);
        float mean = s0 * (1.f/128.f);
        float s1 = 0.f;
        #pragma unroll
        for (int kst = 0; kst < 4; ++kst)
            #pragma unroll
            for (int h = 0; h < 2; ++h) {
                float4 v = A[mt][kst][h];
                float a = v.x-mean, b = v.y-mean, c = v.z-mean, d = v.w-mean;
                s1 += a*a + b*b + c*c + d*d;
            }
        s1 += __shfl_xor(s1, 16); s1 += __shfl_xor(s1, 32);
        float rstd = rsqrtf(s1 * (1.f/128.f) + LNEPS);
        float s2 = 0.f;
        #pragma unroll
        for (int kst = 0; kst < 4; ++kst)
            #pragma unroll
            for (int h = 0; h < 2; ++h) {
                float4 v = A[mt][kst][h];
                float4 g = G[kst][h], bb = Bb[kst][h];
                v.x = (v.x-mean)*rstd*g.x + bb.x;
                v.y = (v.y-mean)*rstd*g.y + bb.y;
                v.z = (v.z-mean)*rstd*g.z + bb.z;
                v.w = (v.w-mean)*rstd*g.w + bb.w;
                A[mt][kst][h] = v;
                s2 += v.x*v.x + v.y*v.y + v.z*v.z + v.w*v.w;
            }
        s2 += __shfl_xor(s2, 16); s2 += __shfl_xor(s2, 32);
        float rl2 = 1.f / fmaxf(sqrtf(s2), 1e-12f);
        #pragma unroll
        for (int kst = 0; kst < 4; ++kst) {
            float4 va = A[mt][kst][0], vb = A[mt][kst][1];
            va.x*=rl2; va.y*=rl2; va.z*=rl2; va.w*=rl2;
            vb.x*=rl2; vb.y*=rl2; vb.z*=rl2; vb.w*=rl2;
            H8U4 h, lo;
            h.h[0]=(_Float16)va.x; h.h[1]=(_Float16)va.y; h.h[2]=(_Float16)va.z; h.h[3]=(_Float16)va.w;
            h.h[4]=(_Float16)vb.x; h.h[5]=(_Float16)vb.y; h.h[6]=(_Float16)vb.z; h.h[7]=(_Float16)vb.w;
            lo.h[0]=(_Float16)(va.x-(float)h.h[0]); lo.h[1]=(_Float16)(va.y-(float)h.h[1]);
            lo.h[2]=(_Float16)(va.z-(float)h.h[2]); lo.h[3]=(_Float16)(va.w-(float)h.h[3]);
            lo.h[4]=(_Float16)(vb.x-(float)h.h[4]); lo.h[5]=(_Float16)(vb.y-(float)h.h[5]);
            lo.h[6]=(_Float16)(vb.z-(float)h.h[6]); lo.h[7]=(_Float16)(vb.w-(float)h.h[7]);
            fah[mt][kst] = h.h;
            fal[mt][kst] = lo.h;
        }
    }

    f32x4 acc[2][13];
    #pragma unroll
    for (int mt = 0; mt < 2; ++mt)
        #pragma unroll
        for (int nt = 0; nt < 13; ++nt)
            acc[mt][nt] = (f32x4){0.f,0.f,0.f,0.f};

    __syncthreads();   // drains B0,B1 (covered by A-load + LN)

    // ---- staged GEMM: issue loads for s+2 at TOP of stage s (3-deep buffers),
    //  so the end-of-stage barrier drain is covered by the MFMA block.
    #pragma unroll
    for (int s = 0; s < 7; ++s) {
        if (s < 5) STAGE_B(s + 2, (s + 2) % 3);
        const uint4* bb = bbuf + (s % 3)*1024;
        if (s < 6) {
            #pragma unroll
            for (int kst = 0; kst < 4; ++kst) {
                const int slz = (kst*4 + l4) ^ l15;
                half8 b0h = lds_h8(bb + l15*16 + slz);
                half8 b0l = lds_h8(bb + 512 + l15*16 + slz);
                half8 b1h = lds_h8(bb + (16+l15)*16 + slz);
                half8 b1l = lds_h8(bb + 512 + (16+l15)*16 + slz);
                acc[0][2*s]   = MFMA_(b0h, fah[0][kst], acc[0][2*s]);
                acc[1][2*s]   = MFMA_(b0h, fah[1][kst], acc[1][2*s]);
                acc[0][2*s+1] = MFMA_(b1h, fah[0][kst], acc[0][2*s+1]);
                acc[1][2*s+1] = MFMA_(b1h, fah[1][kst], acc[1][2*s+1]);
                acc[0][2*s]   = MFMA_(b0h, fal[0][kst], acc[0][2*s]);
                acc[1][2*s]   = MFMA_(b0h, fal[1][kst], acc[1][2*s]);
                acc[0][2*s+1] = MFMA_(b1h, fal[0][kst], acc[0][2*s+1]);
                acc[1][2*s+1] = MFMA_(b1h, fal[1][kst], acc[1][2*s+1]);
                acc[0][2*s]   = MFMA_(b0l, fah[0][kst], acc[0][2*s]);
                acc[1][2*s]   = MFMA_(b0l, fah[1][kst], acc[1][2*s]);
                acc[0][2*s+1] = MFMA_(b1l, fah[0][kst], acc[0][2*s+1]);
                acc[1][2*s+1] = MFMA_(b1l, fah[1][kst], acc[1][2*s+1]);
                acc[0][2*s]   = MFMA_(b0l, fal[0][kst], acc[0][2*s]);
                acc[1][2*s]   = MFMA_(b0l, fal[1][kst], acc[1][2*s]);
                acc[0][2*s+1] = MFMA_(b1l, fal[0][kst], acc[0][2*s+1]);
                acc[1][2*s+1] = MFMA_(b1l, fal[1][kst], acc[1][2*s+1]);
            }
        } else {
            #pragma unroll
            for (int kst = 0; kst < 4; ++kst) {
                const int slz = (kst*4 + l4) ^ l15;
                half8 b0h = lds_h8(bb + l15*16 + slz);
                half8 b0l = lds_h8(bb + 512 + l15*16 + slz);
                acc[0][12] = MFMA_(b0h, fah[0][kst], acc[0][12]);
                acc[1][12] = MFMA_(b0h, fah[1][kst], acc[1][12]);
                acc[0][12] = MFMA_(b0h, fal[0][kst], acc[0][12]);
                acc[1][12] = MFMA_(b0h, fal[1][kst], acc[1][12]);
                acc[0][12] = MFMA_(b0l, fah[0][kst], acc[0][12]);
                acc[1][12] = MFMA_(b0l, fah[1][kst], acc[1][12]);
                acc[0][12] = MFMA_(b0l, fal[0][kst], acc[0][12]);
                acc[1][12] = MFMA_(b0l, fal[1][kst], acc[1][12]);
            }
        }
        __syncthreads();
    }

    // ---- epilogue FIRST (no big write stream pending): 4 passes of 32 pts
    //  via dead-B LDS region. plog stores deferred to the very end.
    #pragma unroll 1
    for (int p = 0; p < 4; ++p) {
        if (w == p) {
            #pragma unroll
            for (int mt = 0; mt < 2; ++mt)
                #pragma unroll
                for (int nt = 0; nt < 13; ++nt)
                    if (nt < 12 || l4 < 2) {
                        float4 sv;
                        sv.x = acc[mt][nt][0]; sv.y = acc[mt][nt][1];
                        sv.z = acc[mt][nt][2]; sv.w = acc[mt][nt][3];
                        *reinterpret_cast<float4*>(
                            &epi[(mt*16 + l15)*210 + nt*16 + l4*4]) = sv;
                    }
        }
        __syncthreads();
        if (t < 128) {
            const int q = t >> 2, sub = t & 3;
            const int n = pbase + p*32 + q;
            float ml[5];
            #pragma unroll
            for (int kk = 0; kk < 5; ++kk) {
                int k = sub*5 + kk;
                float mx = epi[q*210 + k*10];
                #pragma unroll
                for (int m = 1; m < 10; ++m) mx = fmaxf(mx, epi[q*210 + k*10 + m]);
                ml[kk] = mx;
            }
            float s0 = ml[0]+ml[1]+ml[2]+ml[3]+ml[4];
            s0 += __shfl_xor(s0,1); s0 += __shfl_xor(s0,2);
            float mean = s0 / 20.f;
            float s1 = 0.f;
            #pragma unroll
            for (int kk = 0; kk < 5; ++kk) { float d = ml[kk]-mean; s1 += d*d; }
            s1 += __shfl_xor(s1,1); s1 += __shfl_xor(s1,2);
            float rstd = rsqrtf(s1 / 20.f + LNEPS);
            float bv = -1e30f; int bk = 0;
            #pragma unroll
            for (int kk = 0; kk < 5; ++kk) {
                int k = sub*5 + kk;
                float y = (ml[kk]-mean)*rstd*mg[k] + mb[k];
                out_seg[(size_t)n*20 + k] = y;
                if (y > bv) { bv = y; bk = k; }
            }
            #pragma unroll
            for (int off = 1; off <= 2; off <<= 1) {   // first-max-wins merge
                float ov = __shfl_xor(bv, off);
                int   ok = __shfl_xor(bk, off);
                if (ov > bv || (ov == bv && ok < bk)) { bv = ov; bk = ok; }
            }
            int g = gt[n];
            if (sub == 0) {
                if (bk == g) {
                    int slot = atomicAdd(ccnt, 1);
                    if (slot < CCAP) cidx[slot] = n;
                }
                float se = 0.f;
                #pragma unroll
                for (int m = 0; m < 10; ++m) {
                    float e = expf(epi[q*210 + g*10 + m] / EPSI);
                    expv[(size_t)n*12 + m] = e;
                    se += e;
                }
                sumS[p*32 + q] = se;
                gtS[p*32 + q]  = g;
            }
        }
        __syncthreads();
    }

    // ---- deterministic per-block class partials over 128 points
    if (t < 160) {
        int c = t >> 3, o = t & 7;
        float cnt = 0.f, sm = 0.f;
        for (int i = o*16; i < o*16 + 16; ++i)
            if (gtS[i] == c) { cnt += 1.f; sm += sumS[i]; }
        part[t] = cnt; part[160 + t] = sm;
    }
    __syncthreads();
    if (t < 20) {
        float cnt = 0.f, sm = 0.f;
        #pragma unroll
        for (int o = 0; o < 8; ++o) { cnt += part[t*8+o]; sm += part[160 + t*8+o]; }
        psb[(size_t)t*2048 + blk]      = cnt;
        psb[(size_t)(20+t)*2048 + blk] = sm;
    }

    // ---- plog stores LAST: the 102KB/block write burst drains at wave exit,
    //  overlapping the other resident block's compute (no barrier waits on it).
    #pragma unroll
    for (int mt = 0; mt < 2; ++mt)
        #pragma unroll
        for (int nt = 0; nt < 13; ++nt)
            if (nt < 12 || l4 < 2) {
                float4 sv;
                sv.x = acc[mt][nt][0]; sv.y = acc[mt][nt][1];
                sv.z = acc[mt][nt][2]; sv.w = acc[mt][nt][3];
                *reinterpret_cast<float4*>(
                    &plog[(size_t)(pbase + w*32 + mt*16 + l15)*200 + nt*16 + l4*4]) = sv;
            }
#undef STAGE_B
}

// ---- reduce class partials -> Bc, sk (deterministic tree)
__global__ __launch_bounds__(256) void k_reduce_sB(
    const float* __restrict__ psb, float* __restrict__ sk, float* __restrict__ Bc)
{
    __shared__ float red[256];
    int t = threadIdx.x, rrow = blockIdx.x;
    float s = 0.f;
    #pragma unroll
    for (int i = 0; i < 8; ++i) s += psb[(size_t)rrow*2048 + i*256 + t];
    red[t] = s; __syncthreads();
    for (int off = 128; off > 0; off >>= 1) { if (t < off) red[t] += red[t+off]; __syncthreads(); }
    if (t == 0) { if (rrow < 20) Bc[rrow] = red[0]; else sk[rrow-20] = red[0]; }
}

// ---- sinkhorn row pass with fused v-chain (iter = 1,2,3)
__global__ __launch_bounds__(256) void k_row(int iter,
    const int* __restrict__ gt, const float* __restrict__ expv,
    const float* __restrict__ uh, const float* __restrict__ sk,
    const float* __restrict__ Bc, float* __restrict__ pr)
{
    __shared__ float prodS[2560];
    __shared__ int gtS[256];
    int t = threadIdx.x, b = blockIdx.x;
    int n = b*256 + t;
    int g = gt[n];
    float e[10];
    {
        const float4* e4 = (const float4*)(expv + (size_t)n*12);
        float4 ea = e4[0], eb = e4[1], ec = e4[2];
        e[0]=ea.x; e[1]=ea.y; e[2]=ea.z; e[3]=ea.w;
        e[4]=eb.x; e[5]=eb.y; e[6]=eb.z; e[7]=eb.w;
        e[8]=ec.x; e[9]=ec.y;
    }
    float skg = sk[g];
    float v = (skg > 0.f) ? 1.f/skg : 1.f;
    float B = Bc[g];
    float Bs = (B > 0.f) ? B : 1.f;
    for (int c = 1; c < iter; ++c) {
        const float* uc = uh + (c-1)*200 + g*10;
        float sc = 0.f;
        #pragma unroll
        for (int m = 0; m < 10; ++m) sc += e[m]*uc[m];
        v = (sc > 0.f) ? 1.f/(Bs*sc) : v/Bs;
    }
    #pragma unroll
    for (int m = 0; m < 10; ++m) prodS[t*10+m] = e[m]*v;
    gtS[t] = g;
    __syncthreads();
    if (t < 200) {
        int kk = t / 10, mm = t % 10;
        float acc = 0.f;
        for (int i = 0; i < 256; ++i)
            if (gtS[i] == kk) acc += prodS[i*10+mm];
        pr[(size_t)t*1024 + b] = acc;
    }
}

// ---- row partials -> u_hist[iter] (faithful rs>0 guard), deterministic
__global__ __launch_bounds__(256) void k_reduce_u(int iter,
    const float* __restrict__ pr, float* __restrict__ uh)
{
    __shared__ float red[256];
    int t = threadIdx.x, j = blockIdx.x;
    float s = 0.f;
    #pragma unroll
    for (int i = 0; i < 4; ++i) s += pr[(size_t)j*1024 + i*256 + t];
    red[t] = s; __syncthreads();
    for (int off = 128; off > 0; off >>= 1) { if (t < off) red[t] += red[t+off]; __syncthreads(); }
    if (t == 0) {
        float S = red[0];
        float uprev = (iter == 1) ? 1.f : uh[(iter-2)*200 + j];
        uh[(iter-1)*200 + j] = (S > 0.f) ? 1.f/(10.f*S) : uprev*0.1f;
    }
}

// ---- assignment + f/ncount accumulation (kernel-boundary coherence, no fences)
__global__ __launch_bounds__(256) void k_post(
    const int* __restrict__ gt, const float* __restrict__ expv,
    const float* __restrict__ u,
    const int* __restrict__ cidx, const int* __restrict__ ccnt,
    const float* __restrict__ feat, const float* __restrict__ fg,
    const float* __restrict__ fb,
    float* __restrict__ ptarget, float* __restrict__ facc,
    float* __restrict__ ncount)
{
    int t = threadIdx.x;
    {
        int n = blockIdx.x*256 + t;
        int g = gt[n];
        const float* uk = u + g*10;
        float bv = -1e30f; int idx = 0;
        #pragma unroll
        for (int m = 0; m < 10; ++m) {
            float pm = expv[(size_t)n*12 + m] * uk[m];
            if (pm > bv) { bv = pm; idx = m; }
        }
        ptarget[n] = (float)(idx + 10*g);
    }
    int wid = blockIdx.x*4 + (t >> 6);
    int lane = t & 63;
    int cnt = *ccnt; if (cnt > CCAP) cnt = CCAP;
    for (int i = wid; i < cnt; i += 4096) {
        int n = cidx[i];
        float x0 = feat[(size_t)n*128 + lane], x1 = feat[(size_t)n*128 + 64 + lane];
        float s = x0 + x1;
        #pragma unroll
        for (int off = 32; off > 0; off >>= 1) s += __shfl_xor(s, off);
        float mean = s * (1.f/128.f);
        float d0 = x0 - mean, d1 = x1 - mean;
        float s2 = d0*d0 + d1*d1;
        #pragma unroll
        for (int off = 32; off > 0; off >>= 1) s2 += __shfl_xor(s2, off);
        float rstd = rsqrtf(s2 * (1.f/128.f) + LNEPS);
        float y0 = d0*rstd*fg[lane] + fb[lane];
        float y1 = d1*rstd*fg[64+lane] + fb[64+lane];
        float s3 = y0*y0 + y1*y1;
        #pragma unroll
        for (int off = 32; off > 0; off >>= 1) s3 += __shfl_xor(s3, off);
        float rl2 = 1.f / fmaxf(sqrtf(s3), 1e-12f);
        float c0 = y0*rl2, c1 = y1*rl2;
        int g = gt[n];
        const float* uk = u + g*10;
        float bv = -1e30f; int idx = 0;
        #pragma unroll
        for (int m = 0; m < 10; ++m) {
            float pm = expv[(size_t)n*12 + m] * uk[m];
            if (pm > bv) { bv = pm; idx = m; }
        }
        float* frow = facc + (size_t)(g*10+idx)*128;
        atomicAdd(&frow[lane], c0);
        atomicAdd(&frow[64+lane], c1);
        if (lane == 0) atomicAdd(&ncount[g*10+idx], 1.f);
    }
}

// ---- momentum update + renormalize prototypes
__global__ __launch_bounds__(64) void k_proto_update(
    const float* __restrict__ facc, const float* __restrict__ ncount,
    const float* __restrict__ pn, float* __restrict__ outp)
{
    const float OMG = (float)(1.0 - 0.99);
    int j = blockIdx.x, l = threadIdx.x;
    float f0 = facc[(size_t)j*128+l], f1 = facc[(size_t)j*128+64+l];
    float ss = f0*f0 + f1*f1;
    #pragma unroll
    for (int off = 32; off > 0; off >>= 1) ss += __shfl_xor(ss, off);
    float fl2 = fmaxf(sqrtf(ss), 1e-12f);
    float fn0 = f0/fl2, fn1 = f1/fl2;
    float p0 = pn[(size_t)j*128+l], p1 = pn[(size_t)j*128+64+l];
    float u0 = 0.99f*p0 + OMG*fn0, u1 = 0.99f*p1 + OMG*fn1;
    bool ok = ncount[j] > 0.f;
    float s0 = ok ? u0 : p0, s1 = ok ? u1 : p1;
    float ss2 = s0*s0 + s1*s1;
    #pragma unroll
    for (int off = 32; off > 0; off >>= 1) ss2 += __shfl_xor(ss2, off);
    float l2 = fmaxf(sqrtf(ss2), 1e-12f);
    outp[(size_t)j*128+l]      = s0/l2;
    outp[(size_t)j*128+64+l]   = s1/l2;
}

extern "C" void kernel_launch(void* const* d_in, const int* in_sizes, int n_in,
                              void* d_out, int out_size, void* d_ws, size_t ws_size,
                              hipStream_t stream)
{
    const float* feat   = (const float*)d_in[0];
    const int*   gt     = (const int*)  d_in[1];
    const float* protos = (const float*)d_in[2];
    const float* fg     = (const float*)d_in[3];
    const float* fb     = (const float*)d_in[4];
    const float* mg     = (const float*)d_in[5];
    const float* mb     = (const float*)d_in[6];

    float* out      = (float*)d_out;
    float* out_seg  = out;
    float* plog     = out + (size_t)NPTS*20;
    float* ptarget  = out + (size_t)NPTS*220;
    float* newp     = out + (size_t)NPTS*221;

    float* ws   = (float*)d_ws;
    float* pn   = ws + WS_PN;
    _Float16* phi = (_Float16*)(ws + WS_PHI);
    _Float16* plo = (_Float16*)(ws + WS_PLO);
    float* facc = ws + WS_F;
    float* ncnt = ws + WS_NCOUNT;
    int*   ccnt = (int*)(ws + WS_CCNT);
    float* uh   = ws + WS_UH;
    float* sk   = ws + WS_SK;
    float* Bc   = ws + WS_BC;
    float* psb  = ws + WS_PSB;
    float* pr   = ws + WS_PR;
    float* expv = ws + WS_EXPV;
    int*   cidx = (int*)(ws + WS_CIDX);

    // zero facc + ncount + ccnt (contiguous)
    hipMemsetAsync(facc, 0, (25600 + 200 + 8)*sizeof(float), stream);
    hipLaunchKernelGGL(k_norm_protos, dim3(224), dim3(64), 0, stream, protos, pn, phi, plo);
    hipLaunchKernelGGL(k_main, dim3(2048), dim3(256), 0, stream,
                       feat, gt, phi, plo, fg, fb, mg, mb, out_seg, plog, expv, psb,
                       cidx, ccnt);
    hipLaunchKernelGGL(k_reduce_sB, dim3(40), dim3(256), 0, stream, psb, sk, Bc);
    for (int it = 1; it <= 3; ++it) {
        hipLaunchKernelGGL(k_row, dim3(1024), dim3(256), 0, stream, it, gt, expv, uh, sk, Bc, pr);
        hipLaunchKernelGGL(k_reduce_u, dim3(200), dim3(256), 0, stream, it, pr, uh);
    }
    hipLaunchKernelGGL(k_post, dim3(1024), dim3(256), 0, stream,
                       gt, expv, uh + 400, cidx, ccnt, feat, fg, fb, ptarget, facc, ncnt);
    hipLaunchKernelGGL(k_proto_update, dim3(200), dim3(64), 0, stream, facc, ncnt, pn, newp);
}

// Round 11
// 270.216 us; speedup vs baseline: 2.9752x; 1.0118x over previous
//
#include <hip/hip_runtime.h>
#include <hip/hip_bf16.h>

#define NPTS 262144
#define DIM  128
#define KC   20
#define MP   10
#define LNEPS 1e-5f
#define EPSI  0.05f
#define CCAP  65536

typedef _Float16 half8 __attribute__((ext_vector_type(8)));
typedef float f32x4 __attribute__((ext_vector_type(4)));

union H8U4 { half8 h; uint4 u; };

// workspace layout (float offsets)
#define WS_PN     0          // 25600 normalized protos f32
#define WS_PHI    25600      // 14336 floats (224x128 f16 hi, PRE-SWIZZLED, rows 200..223 zero)
#define WS_PLO    39936      // 14336 floats (f16 lo, PRE-SWIZZLED)
#define WS_F      54272      // 25600 f accumulator
#define WS_NCOUNT 79872      // 200
#define WS_CCNT   80072      // 8 ints (ccnt + pad)
#define WS_UH     80080      // 600 u history (3 x 200)
#define WS_SK     80680      // 20
#define WS_BC     80700      // 20
#define WS_PSB    80720      // 40*4096 partials
#define WS_PR     244560     // 200*1024 row-sum partials
#define WS_EXPV   449360     // N*12 (10 + 2 pad)
#define WS_CIDX   3595088    // 65536 ints
// total 3660624 floats = 14.6 MB

#define MFMA_(b_, a_, c_) __builtin_amdgcn_mfma_f32_16x16x32_f16(b_, a_, c_, 0, 0, 0)

__device__ __forceinline__ half8 lds_h8(const uint4* p) {
    return *reinterpret_cast<const half8*>(p);
}

// async global->LDS, 16B per lane; LDS dest = wave-uniform base + lane*16
__device__ __forceinline__ void gload_lds16(const uint4* g, uint4* l) {
    __builtin_amdgcn_global_load_lds(
        (const __attribute__((address_space(1))) void*)(g),
        (__attribute__((address_space(3))) void*)(l), 16, 0, 0);
}

// ---- normalize prototypes; emit f32 (pn) + PRE-SWIZZLED f16 hi/lo.
//  Swizzle (u4-granular): row j, u4-slot s -> slot s ^ (j&15), so a LINEAR
//  global_load_lds of a 32-row stage lands in LDS in MFMA-reader layout.
__global__ __launch_bounds__(64) void k_norm_protos(
    const float* __restrict__ pr, float* __restrict__ pn,
    _Float16* __restrict__ phi, _Float16* __restrict__ plo)
{
    int j = blockIdx.x, l = threadIdx.x;
    const int jm = j & 15;
    const int s1 = l >> 3,       swz1 = (((s1 ^ jm) << 3) | (l & 7));
    const int s2 = 8 + (l >> 3), swz2 = (((s2 ^ jm) << 3) | (l & 7));
    if (j < 200) {
        float x0 = pr[(size_t)j*128 + l], x1 = pr[(size_t)j*128 + 64 + l];
        float ss = x0*x0 + x1*x1;
        #pragma unroll
        for (int off = 32; off > 0; off >>= 1) ss += __shfl_xor(ss, off);
        float dn = fmaxf(sqrtf(ss), 1e-12f);
        float y0 = x0/dn, y1 = x1/dn;
        pn[(size_t)j*128 + l]      = y0;
        pn[(size_t)j*128 + 64 + l] = y1;
        _Float16 h0 = (_Float16)y0, h1 = (_Float16)y1;
        phi[(size_t)j*128 + swz1] = h0;
        phi[(size_t)j*128 + swz2] = h1;
        plo[(size_t)j*128 + swz1] = (_Float16)(y0 - (float)h0);
        plo[(size_t)j*128 + swz2] = (_Float16)(y1 - (float)h1);
    } else {
        phi[(size_t)j*128 + swz1] = (_Float16)0.f;  phi[(size_t)j*128 + swz2] = (_Float16)0.f;
        plo[(size_t)j*128 + swz1] = (_Float16)0.f;  plo[(size_t)j*128 + swz2] = (_Float16)0.f;
    }
}

// ---- main kernel: 4096 blocks x 256 thr (4 waves), 64 pts/block.
//  Wave tile = 16 pts x 208 cols: acc 52 + frags 32 regs -> 3 waves/SIMD.
//  A: direct per-lane global fragment loads + shfl LN (no LDS, no barriers).
//  B: global_load_lds, 3-deep buffers, loads issued at TOP of stage.
//  Epilogue from acc via dead-B LDS (2 passes of 32 pts); plog stores LAST.
__global__ __launch_bounds__(256, 3) void k_main(
    const float* __restrict__ feat, const int* __restrict__ gt,
    const _Float16* __restrict__ phi, const _Float16* __restrict__ plo,
    const float* __restrict__ fg, const float* __restrict__ fb,
    const float* __restrict__ mg, const float* __restrict__ mb,
    float* __restrict__ out_seg, float* __restrict__ plog,
    float* __restrict__ expv, float* __restrict__ psb,
    int* __restrict__ cidx, int* __restrict__ ccnt)
{
    __shared__ __align__(16) char ldsb[49152];   // 3 x 16KB B buffers; epi reuse
    __shared__ float sumS[64];
    __shared__ int   gtS[64];
    __shared__ float part[320];
    uint4* bbuf = (uint4*)ldsb;                  // buf b at +b*1024 u4; hi +0, lo +512
    float* epi  = (float*)ldsb;                  // [32][210] after GEMM

    const int t = threadIdx.x, blk = blockIdx.x;
    const int w = t >> 6, lane = t & 63;
    const int l15 = lane & 15, l4 = lane >> 4;
    const int pbase = blk * 64;

    const uint4* phi4 = (const uint4*)phi;
    const uint4* plo4 = (const uint4*)plo;

#define STAGE_B(S, BI) do { \
        const uint4* gh = phi4 + (size_t)(S)*512 + t; \
        const uint4* gl = plo4 + (size_t)(S)*512 + t; \
        uint4* dh = bbuf + (BI)*1024 + w*64; \
        uint4* dl = bbuf + (BI)*1024 + 512 + w*64; \
        gload_lds16(gh,       dh); \
        gload_lds16(gh + 256, dh + 256); \
        gload_lds16(gl,       dl); \
        gload_lds16(gl + 256, dl + 256); \
    } while (0)

    // prologue: issue B0, B1 (in flight under A-load + LN)
    STAGE_B(0, 0);
    STAGE_B(1, 1);

    // ---- A direct loads in fragment layout: row = pbase + w*16 + l15
    const float4* gfeat = (const float4*)feat;
    float4 A[4][2];
    {
        size_t rb = (size_t)(pbase + w*16 + l15) * 32;
        #pragma unroll
        for (int kst = 0; kst < 4; ++kst)
            #pragma unroll
            for (int h = 0; h < 2; ++h)
                A[kst][h] = gfeat[rb + kst*8 + l4*2 + h];
    }
    float4 G[4][2], Bb[4][2];
    {
        const float4* fg4 = (const float4*)fg;
        const float4* fb4 = (const float4*)fb;
        #pragma unroll
        for (int kst = 0; kst < 4; ++kst)
            #pragma unroll
            for (int h = 0; h < 2; ++h) {
                G[kst][h]  = fg4[kst*8 + l4*2 + h];
                Bb[kst][h] = fb4[kst*8 + l4*2 + h];
            }
    }

    // ---- LN + l2n (4-lane group reduce over lanes {l15,+16,+32,+48})
    half8 fah[4], fal[4];
    {
        float s0 = 0.f;
        #pragma unroll
        for (int kst = 0; kst < 4; ++kst)
            #pragma unroll
            for (int h = 0; h < 2; ++h) {
                float4 v = A[kst][h];
                s0 += v.x + v.y + v.z + v.w;
            }
        s0 += __shfl_xor(s0, 16); s0 += __shfl_xor(s0, 32);
        float mean = s0 * (1.f/128.f);
        float s1 = 0.f;
        #pragma unroll
        for (int kst = 0; kst < 4; ++kst)
            #pragma unroll
            for (int h = 0; h < 2; ++h) {
                float4 v = A[kst][h];
                float a = v.x-mean, b = v.y-mean, c = v.z-mean, d = v.w-mean;
                s1 += a*a + b*b + c*c + d*d;
            }
        s1 += __shfl_xor(s1, 16); s1 += __shfl_xor(s1, 32);
        float rstd = rsqrtf(s1 * (1.f/128.f) + LNEPS);
        float s2 = 0.f;
        #pragma unroll
        for (int kst = 0; kst < 4; ++kst)
            #pragma unroll
            for (int h = 0; h < 2; ++h) {
                float4 v = A[kst][h];
                float4 g = G[kst][h], bb = Bb[kst][h];
                v.x = (v.x-mean)*rstd*g.x + bb.x;
                v.y = (v.y-mean)*rstd*g.y + bb.y;
                v.z = (v.z-mean)*rstd*g.z + bb.z;
                v.w = (v.w-mean)*rstd*g.w + bb.w;
                A[kst][h] = v;
                s2 += v.x*v.x + v.y*v.y + v.z*v.z + v.w*v.w;
            }
        s2 += __shfl_xor(s2, 16); s2 += __shfl_xor(s2, 32);
        float rl2 = 1.f / fmaxf(sqrtf(s2), 1e-12f);
        #pragma unroll
        for (int kst = 0; kst < 4; ++kst) {
            float4 va = A[kst][0], vb = A[kst][1];
            va.x*=rl2; va.y*=rl2; va.z*=rl2; va.w*=rl2;
            vb.x*=rl2; vb.y*=rl2; vb.z*=rl2; vb.w*=rl2;
            H8U4 h, lo;
            h.h[0]=(_Float16)va.x; h.h[1]=(_Float16)va.y; h.h[2]=(_Float16)va.z; h.h[3]=(_Float16)va.w;
            h.h[4]=(_Float16)vb.x; h.h[5]=(_Float16)vb.y; h.h[6]=(_Float16)vb.z; h.h[7]=(_Float16)vb.w;
            lo.h[0]=(_Float16)(va.x-(float)h.h[0]); lo.h[1]=(_Float16)(va.y-(float)h.h[1]);
            lo.h[2]=(_Float16)(va.z-(float)h.h[2]); lo.h[3]=(_Float16)(va.w-(float)h.h[3]);
            lo.h[4]=(_Float16)(vb.x-(float)h.h[4]); lo.h[5]=(_Float16)(vb.y-(float)h.h[5]);
            lo.h[6]=(_Float16)(vb.z-(float)h.h[6]); lo.h[7]=(_Float16)(vb.w-(float)h.h[7]);
            fah[kst] = h.h;
            fal[kst] = lo.h;
        }
    }

    f32x4 acc[13];
    #pragma unroll
    for (int nt = 0; nt < 13; ++nt)
        acc[nt] = (f32x4){0.f,0.f,0.f,0.f};

    __syncthreads();   // drains B0,B1 (covered by A-load + LN)

    // ---- staged GEMM: issue loads for s+2 at TOP of stage s (3-deep buffers)
    #pragma unroll
    for (int s = 0; s < 7; ++s) {
        if (s < 5) STAGE_B(s + 2, (s + 2) % 3);
        const uint4* bb = bbuf + (s % 3)*1024;
        if (s < 6) {
            #pragma unroll
            for (int kst = 0; kst < 4; ++kst) {
                const int slz = (kst*4 + l4) ^ l15;
                half8 b0h = lds_h8(bb + l15*16 + slz);
                half8 b0l = lds_h8(bb + 512 + l15*16 + slz);
                half8 b1h = lds_h8(bb + (16+l15)*16 + slz);
                half8 b1l = lds_h8(bb + 512 + (16+l15)*16 + slz);
                acc[2*s]   = MFMA_(b0h, fah[kst], acc[2*s]);
                acc[2*s+1] = MFMA_(b1h, fah[kst], acc[2*s+1]);
                acc[2*s]   = MFMA_(b0h, fal[kst], acc[2*s]);
                acc[2*s+1] = MFMA_(b1h, fal[kst], acc[2*s+1]);
                acc[2*s]   = MFMA_(b0l, fah[kst], acc[2*s]);
                acc[2*s+1] = MFMA_(b1l, fah[kst], acc[2*s+1]);
                acc[2*s]   = MFMA_(b0l, fal[kst], acc[2*s]);
                acc[2*s+1] = MFMA_(b1l, fal[kst], acc[2*s+1]);
            }
        } else {
            #pragma unroll
            for (int kst = 0; kst < 4; ++kst) {
                const int slz = (kst*4 + l4) ^ l15;
                half8 b0h = lds_h8(bb + l15*16 + slz);
                half8 b0l = lds_h8(bb + 512 + l15*16 + slz);
                acc[12] = MFMA_(b0h, fah[kst], acc[12]);
                acc[12] = MFMA_(b0h, fal[kst], acc[12]);
                acc[12] = MFMA_(b0l, fah[kst], acc[12]);
                acc[12] = MFMA_(b0l, fal[kst], acc[12]);
            }
        }
        __syncthreads();
    }

    // ---- epilogue: 2 passes of 32 pts via dead-B LDS ([32][210])
    #pragma unroll 1
    for (int p = 0; p < 2; ++p) {
        if ((w >> 1) == p) {
            int row = (w & 1)*16 + l15;
            #pragma unroll
            for (int nt = 0; nt < 13; ++nt)
                if (nt < 12 || l4 < 2) {
                    float4 sv;
                    sv.x = acc[nt][0]; sv.y = acc[nt][1];
                    sv.z = acc[nt][2]; sv.w = acc[nt][3];
                    *reinterpret_cast<float4*>(&epi[row*210 + nt*16 + l4*4]) = sv;
                }
        }
        __syncthreads();
        if (t < 128) {
            const int q = t >> 2, sub = t & 3;
            const int n = pbase + p*32 + q;
            float ml[5];
            #pragma unroll
            for (int kk = 0; kk < 5; ++kk) {
                int k = sub*5 + kk;
                float mx = epi[q*210 + k*10];
                #pragma unroll
                for (int m = 1; m < 10; ++m) mx = fmaxf(mx, epi[q*210 + k*10 + m]);
                ml[kk] = mx;
            }
            float s0 = ml[0]+ml[1]+ml[2]+ml[3]+ml[4];
            s0 += __shfl_xor(s0,1); s0 += __shfl_xor(s0,2);
            float mean = s0 / 20.f;
            float s1 = 0.f;
            #pragma unroll
            for (int kk = 0; kk < 5; ++kk) { float d = ml[kk]-mean; s1 += d*d; }
            s1 += __shfl_xor(s1,1); s1 += __shfl_xor(s1,2);
            float rstd = rsqrtf(s1 / 20.f + LNEPS);
            float bv = -1e30f; int bk = 0;
            #pragma unroll
            for (int kk = 0; kk < 5; ++kk) {
                int k = sub*5 + kk;
                float y = (ml[kk]-mean)*rstd*mg[k] + mb[k];
                out_seg[(size_t)n*20 + k] = y;
                if (y > bv) { bv = y; bk = k; }
            }
            #pragma unroll
            for (int off = 1; off <= 2; off <<= 1) {   // first-max-wins merge
                float ov = __shfl_xor(bv, off);
                int   ok = __shfl_xor(bk, off);
                if (ov > bv || (ov == bv && ok < bk)) { bv = ov; bk = ok; }
            }
            int g = gt[n];
            if (sub == 0) {
                if (bk == g) {
                    int slot = atomicAdd(ccnt, 1);
                    if (slot < CCAP) cidx[slot] = n;
                }
                float se = 0.f;
                #pragma unroll
                for (int m = 0; m < 10; ++m) {
                    float e = expf(epi[q*210 + g*10 + m] / EPSI);
                    expv[(size_t)n*12 + m] = e;
                    se += e;
                }
                sumS[p*32 + q] = se;
                gtS[p*32 + q]  = g;
            }
        }
        __syncthreads();
    }

    // ---- deterministic per-block class partials over 64 points
    if (t < 160) {
        int c = t >> 3, o = t & 7;
        float cnt = 0.f, sm = 0.f;
        for (int i = o*8; i < o*8 + 8; ++i)
            if (gtS[i] == c) { cnt += 1.f; sm += sumS[i]; }
        part[t] = cnt; part[160 + t] = sm;
    }
    __syncthreads();
    if (t < 20) {
        float cnt = 0.f, sm = 0.f;
        #pragma unroll
        for (int o = 0; o < 8; ++o) { cnt += part[t*8+o]; sm += part[160 + t*8+o]; }
        psb[(size_t)t*4096 + blk]      = cnt;
        psb[(size_t)(20+t)*4096 + blk] = sm;
    }

    // ---- plog stores LAST: write burst drains at wave exit (no barrier waits)
    #pragma unroll
    for (int nt = 0; nt < 13; ++nt)
        if (nt < 12 || l4 < 2) {
            float4 sv;
            sv.x = acc[nt][0]; sv.y = acc[nt][1];
            sv.z = acc[nt][2]; sv.w = acc[nt][3];
            *reinterpret_cast<float4*>(
                &plog[(size_t)(pbase + w*16 + l15)*200 + nt*16 + l4*4]) = sv;
        }
#undef STAGE_B
}

// ---- reduce class partials -> Bc, sk (deterministic tree)
__global__ __launch_bounds__(256) void k_reduce_sB(
    const float* __restrict__ psb, float* __restrict__ sk, float* __restrict__ Bc)
{
    __shared__ float red[256];
    int t = threadIdx.x, rrow = blockIdx.x;
    float s = 0.f;
    #pragma unroll
    for (int i = 0; i < 16; ++i) s += psb[(size_t)rrow*4096 + i*256 + t];
    red[t] = s; __syncthreads();
    for (int off = 128; off > 0; off >>= 1) { if (t < off) red[t] += red[t+off]; __syncthreads(); }
    if (t == 0) { if (rrow < 20) Bc[rrow] = red[0]; else sk[rrow-20] = red[0]; }
}

// ---- sinkhorn row pass with fused v-chain (iter = 1,2,3)
__global__ __launch_bounds__(256) void k_row(int iter,
    const int* __restrict__ gt, const float* __restrict__ expv,
    const float* __restrict__ uh, const float* __restrict__ sk,
    const float* __restrict__ Bc, float* __restrict__ pr)
{
    __shared__ float prodS[2560];
    __shared__ int gtS[256];
    int t = threadIdx.x, b = blockIdx.x;
    int n = b*256 + t;
    int g = gt[n];
    float e[10];
    {
        const float4* e4 = (const float4*)(expv + (size_t)n*12);
        float4 ea = e4[0], eb = e4[1], ec = e4[2];
        e[0]=ea.x; e[1]=ea.y; e[2]=ea.z; e[3]=ea.w;
        e[4]=eb.x; e[5]=eb.y; e[6]=eb.z; e[7]=eb.w;
        e[8]=ec.x; e[9]=ec.y;
    }
    float skg = sk[g];
    float v = (skg > 0.f) ? 1.f/skg : 1.f;
    float B = Bc[g];
    float Bs = (B > 0.f) ? B : 1.f;
    for (int c = 1; c < iter; ++c) {
        const float* uc = uh + (c-1)*200 + g*10;
        float sc = 0.f;
        #pragma unroll
        for (int m = 0; m < 10; ++m) sc += e[m]*uc[m];
        v = (sc > 0.f) ? 1.f/(Bs*sc) : v/Bs;
    }
    #pragma unroll
    for (int m = 0; m < 10; ++m) prodS[t*10+m] = e[m]*v;
    gtS[t] = g;
    __syncthreads();
    if (t < 200) {
        int kk = t / 10, mm = t % 10;
        float acc = 0.f;
        for (int i = 0; i < 256; ++i)
            if (gtS[i] == kk) acc += prodS[i*10+mm];
        pr[(size_t)t*1024 + b] = acc;
    }
}

// ---- row partials -> u_hist[iter] (faithful rs>0 guard), deterministic
__global__ __launch_bounds__(256) void k_reduce_u(int iter,
    const float* __restrict__ pr, float* __restrict__ uh)
{
    __shared__ float red[256];
    int t = threadIdx.x, j = blockIdx.x;
    float s = 0.f;
    #pragma unroll
    for (int i = 0; i < 4; ++i) s += pr[(size_t)j*1024 + i*256 + t];
    red[t] = s; __syncthreads();
    for (int off = 128; off > 0; off >>= 1) { if (t < off) red[t] += red[t+off]; __syncthreads(); }
    if (t == 0) {
        float S = red[0];
        float uprev = (iter == 1) ? 1.f : uh[(iter-2)*200 + j];
        uh[(iter-1)*200 + j] = (S > 0.f) ? 1.f/(10.f*S) : uprev*0.1f;
    }
}

// ---- assignment + f/ncount accumulation (kernel-boundary coherence, no fences)
__global__ __launch_bounds__(256) void k_post(
    const int* __restrict__ gt, const float* __restrict__ expv,
    const float* __restrict__ u,
    const int* __restrict__ cidx, const int* __restrict__ ccnt,
    const float* __restrict__ feat, const float* __restrict__ fg,
    const float* __restrict__ fb,
    float* __restrict__ ptarget, float* __restrict__ facc,
    float* __restrict__ ncount)
{
    int t = threadIdx.x;
    {
        int n = blockIdx.x*256 + t;
        int g = gt[n];
        const float* uk = u + g*10;
        float bv = -1e30f; int idx = 0;
        #pragma unroll
        for (int m = 0; m < 10; ++m) {
            float pm = expv[(size_t)n*12 + m] * uk[m];
            if (pm > bv) { bv = pm; idx = m; }
        }
        ptarget[n] = (float)(idx + 10*g);
    }
    int wid = blockIdx.x*4 + (t >> 6);
    int lane = t & 63;
    int cnt = *ccnt; if (cnt > CCAP) cnt = CCAP;
    for (int i = wid; i < cnt; i += 4096) {
        int n = cidx[i];
        float x0 = feat[(size_t)n*128 + lane], x1 = feat[(size_t)n*128 + 64 + lane];
        float s = x0 + x1;
        #pragma unroll
        for (int off = 32; off > 0; off >>= 1) s += __shfl_xor(s, off);
        float mean = s * (1.f/128.f);
        float d0 = x0 - mean, d1 = x1 - mean;
        float s2 = d0*d0 + d1*d1;
        #pragma unroll
        for (int off = 32; off > 0; off >>= 1) s2 += __shfl_xor(s2, off);
        float rstd = rsqrtf(s2 * (1.f/128.f) + LNEPS);
        float y0 = d0*rstd*fg[lane] + fb[lane];
        float y1 = d1*rstd*fg[64+lane] + fb[64+lane];
        float s3 = y0*y0 + y1*y1;
        #pragma unroll
        for (int off = 32; off > 0; off >>= 1) s3 += __shfl_xor(s3, off);
        float rl2 = 1.f / fmaxf(sqrtf(s3), 1e-12f);
        float c0 = y0*rl2, c1 = y1*rl2;
        int g = gt[n];
        const float* uk = u + g*10;
        float bv = -1e30f; int idx = 0;
        #pragma unroll
        for (int m = 0; m < 10; ++m) {
            float pm = expv[(size_t)n*12 + m] * uk[m];
            if (pm > bv) { bv = pm; idx = m; }
        }
        float* frow = facc + (size_t)(g*10+idx)*128;
        atomicAdd(&frow[lane], c0);
        atomicAdd(&frow[64+lane], c1);
        if (lane == 0) atomicAdd(&ncount[g*10+idx], 1.f);
    }
}

// ---- momentum update + renormalize prototypes
__global__ __launch_bounds__(64) void k_proto_update(
    const float* __restrict__ facc, const float* __restrict__ ncount,
    const float* __restrict__ pn, float* __restrict__ outp)
{
    const float OMG = (float)(1.0 - 0.99);
    int j = blockIdx.x, l = threadIdx.x;
    float f0 = facc[(size_t)j*128+l], f1 = facc[(size_t)j*128+64+l];
    float ss = f0*f0 + f1*f1;
    #pragma unroll
    for (int off = 32; off > 0; off >>= 1) ss += __shfl_xor(ss, off);
    float fl2 = fmaxf(sqrtf(ss), 1e-12f);
    float fn0 = f0/fl2, fn1 = f1/fl2;
    float p0 = pn[(size_t)j*128+l], p1 = pn[(size_t)j*128+64+l];
    float u0 = 0.99f*p0 + OMG*fn0, u1 = 0.99f*p1 + OMG*fn1;
    bool ok = ncount[j] > 0.f;
    float s0 = ok ? u0 : p0, s1 = ok ? u1 : p1;
    float ss2 = s0*s0 + s1*s1;
    #pragma unroll
    for (int off = 32; off > 0; off >>= 1) ss2 += __shfl_xor(ss2, off);
    float l2 = fmaxf(sqrtf(ss2), 1e-12f);
    outp[(size_t)j*128+l]      = s0/l2;
    outp[(size_t)j*128+64+l]   = s1/l2;
}

extern "C" void kernel_launch(void* const* d_in, const int* in_sizes, int n_in,
                              void* d_out, int out_size, void* d_ws, size_t ws_size,
                              hipStream_t stream)
{
    const float* feat   = (const float*)d_in[0];
    const int*   gt     = (const int*)  d_in[1];
    const float* protos = (const float*)d_in[2];
    const float* fg     = (const float*)d_in[3];
    const float* fb     = (const float*)d_in[4];
    const float* mg     = (const float*)d_in[5];
    const float* mb     = (const float*)d_in[6];

    float* out      = (float*)d_out;
    float* out_seg  = out;
    float* plog     = out + (size_t)NPTS*20;
    float* ptarget  = out + (size_t)NPTS*220;
    float* newp     = out + (size_t)NPTS*221;

    float* ws   = (float*)d_ws;
    float* pn   = ws + WS_PN;
    _Float16* phi = (_Float16*)(ws + WS_PHI);
    _Float16* plo = (_Float16*)(ws + WS_PLO);
    float* facc = ws + WS_F;
    float* ncnt = ws + WS_NCOUNT;
    int*   ccnt = (int*)(ws + WS_CCNT);
    float* uh   = ws + WS_UH;
    float* sk   = ws + WS_SK;
    float* Bc   = ws + WS_BC;
    float* psb  = ws + WS_PSB;
    float* pr   = ws + WS_PR;
    float* expv = ws + WS_EXPV;
    int*   cidx = (int*)(ws + WS_CIDX);

    // zero facc + ncount + ccnt (contiguous)
    hipMemsetAsync(facc, 0, (25600 + 200 + 8)*sizeof(float), stream);
    hipLaunchKernelGGL(k_norm_protos, dim3(224), dim3(64), 0, stream, protos, pn, phi, plo);
    hipLaunchKernelGGL(k_main, dim3(4096), dim3(256), 0, stream,
                       feat, gt, phi, plo, fg, fb, mg, mb, out_seg, plog, expv, psb,
                       cidx, ccnt);
    hipLaunchKernelGGL(k_reduce_sB, dim3(40), dim3(256), 0, stream, psb, sk, Bc);
    for (int it = 1; it <= 3; ++it) {
        hipLaunchKernelGGL(k_row, dim3(1024), dim3(256), 0, stream, it, gt, expv, uh, sk, Bc, pr);
        hipLaunchKernelGGL(k_reduce_u, dim3(200), dim3(256), 0, stream, it, pr, uh);
    }
    hipLaunchKernelGGL(k_post, dim3(1024), dim3(256), 0, stream,
                       gt, expv, uh + 400, cidx, ccnt, feat, fg, fb, ptarget, facc, ncnt);
    hipLaunchKernelGGL(k_proto_update, dim3(200), dim3(64), 0, stream, facc, ncnt, pn, newp);
}